// Round 6
// baseline (455.692 us; speedup 1.0000x reference)
//
#include <hip/hip_runtime.h>

typedef unsigned short u16;
typedef unsigned int u32;
typedef unsigned long long u64;

#define B_   16
#define C_   384
#define H_   28
#define W_   28
#define S_   784
#define NH_  6
#define HD_  64
#define BS_  (B_ * S_)            // 12544
#define SCALE_ 0.05103103630798288f  // 384^-0.5
#define LSC_   0.07362225484151387f  // SCALE_ * log2(e): exp(s*SCALE) = 2^(s*LSC)
#define EPS_ 1e-5f

typedef __attribute__((ext_vector_type(8))) short bf16x8;
typedef __attribute__((ext_vector_type(4))) float f32x4;

__device__ __forceinline__ float bf2f(u16 u) {
    return __uint_as_float(((u32)u) << 16);
}
__device__ __forceinline__ u16 f2bf(float f) {
    u32 x = __float_as_uint(f);
    u32 r = (x + 0x7fffu + ((x >> 16) & 1u)) >> 16;   // RNE
    return (u16)r;
}

// async global->LDS 16B per lane; dest = wave-uniform base + lane*16 (HW rule)
__device__ __forceinline__ void gld16(const u16* g, u16* l) {
    __builtin_amdgcn_global_load_lds(
        (__attribute__((address_space(1))) void*)g,
        (__attribute__((address_space(3))) void*)l, 16, 0, 0);
}

__device__ __forceinline__ float exp2_fast(float x) {
    float r;
    asm("v_exp_f32 %0, %1" : "=v"(r) : "v"(x));
    return r;
}

// ---------------------------------------------------------------------------
// Kernel 2 (fused, 3-in-1 by input group): depthwise 3x3 conv.
// R6 change: FULL UNROLL of the w-loop + 5-column software-pipeline ring.
// The rolled loop had load->use distance of 1 iter (~66cy VALU) vs ~200cy+
// L2 latency -> per-iteration stall. Ring c0..c4 = cols w-1..w+3; col w+4
// is loaded at the end of iter w and consumed 3 iters later (~200cy).
// FP compute sequence identical to the rolled version.
// ---------------------------------------------------------------------------
__launch_bounds__(384)
__global__ void k_conv(const float* __restrict__ x1, const float* __restrict__ x2,
                       const float* __restrict__ dw, u16* __restrict__ y,
                       float* __restrict__ part) {
    int c = threadIdx.x;            // 0..383
    int id = blockIdx.x;            // 0..1343
    int xcd = id & 7;
    int j = id >> 3;                // 0..167
    int p = xcd + 8 * (j / 28);     // 0..47
    int h = j % 28;                 // 0..27
    int g = p / 16;                 // input group (wave-uniform)
    int b = p % 16;

    const float* pa = x1 + (size_t)b * S_ * C_ + c;
    const float* pb = x2 + (size_t)b * S_ * C_ + c;

    float wt[3][9];
#pragma unroll
    for (int i = 0; i < 3; ++i)
#pragma unroll
        for (int t = 0; t < 9; ++t)
            wt[i][t] = dw[((3 * g + i) * C_ + c) * 9 + t];

    // column loader: 3 rows of column cw (0 outside image); summed for g=2
    auto ldcol = [&](int cw, float* d) {
#pragma unroll
        for (int dh = 0; dh < 3; ++dh) {
            int hh = h + dh - 1;
            float v = 0.f;
            if (cw >= 0 && cw < W_ && hh >= 0 && hh < H_) {
                size_t off = (size_t)(hh * W_ + cw) * C_;
                if (g == 0)      v = pa[off];
                else if (g == 1) v = pb[off];
                else             v = pa[off] + pb[off];
            }
            d[dh] = v;
        }
    };

    float c0[3], c1[3], c2[3], c3[3], c4[3];
    ldcol(-1, c0);      // zeros
    ldcol(0, c1);
    ldcol(1, c2);
    ldcol(2, c3);
    ldcol(3, c4);

    u16* dst[3];
#pragma unroll
    for (int i = 0; i < 3; ++i)
        dst[i] = y + ((size_t)((3 * g + i) * B_ + b) * S_ + h * W_) * C_ + c;

    float sum[3] = {0.f, 0.f, 0.f}, sq[3] = {0.f, 0.f, 0.f};

#pragma unroll
    for (int w = 0; w < W_; ++w) {
#pragma unroll
        for (int i = 0; i < 3; ++i) {
            const float* W9 = wt[i];
            float acc = c0[0]*W9[0] + c1[0]*W9[1] + c2[0]*W9[2]
                      + c0[1]*W9[3] + c1[1]*W9[4] + c2[1]*W9[5]
                      + c0[2]*W9[6] + c1[2]*W9[7] + c2[2]*W9[8];
            sum[i] += acc;
            sq[i] = fmaf(acc, acc, sq[i]);
            dst[i][w * C_] = f2bf(acc);
        }
        // shift ring; load col w+4 (consumed at iter w+3)
#pragma unroll
        for (int dh = 0; dh < 3; ++dh) {
            c0[dh] = c1[dh]; c1[dh] = c2[dh];
            c2[dh] = c3[dh]; c3[dh] = c4[dh];
        }
        ldcol(w + 4, c4);
    }
#pragma unroll
    for (int i = 0; i < 3; ++i) {
        atomicAdd(&part[((3 * g + i) * C_ + c) * 2],     sum[i]);
        atomicAdd(&part[((3 * g + i) * C_ + c) * 2 + 1], sq[i]);
    }
}

// ---------------------------------------------------------------------------
// Kernel 3: finalize folded BN affine from fused partials. grid (9), 384 thr.
// ---------------------------------------------------------------------------
__global__ void k_stats2(const float* __restrict__ part,
                         const float* __restrict__ gamma, const float* __restrict__ beta,
                         float* __restrict__ aScale, float* __restrict__ bShift) {
    int c = threadIdx.x;
    int idx = blockIdx.x;
    float s = part[(idx * C_ + c) * 2];
    float q = part[(idx * C_ + c) * 2 + 1];
    float mean = s / (float)BS_;
    float var  = q / (float)BS_ - mean * mean;
    float a = gamma[idx * C_ + c] * rsqrtf(var + EPS_);
    aScale[idx * C_ + c] = a;
    bShift[idx * C_ + c] = beta[idx * C_ + c] - mean * a;
}

// ---------------------------------------------------------------------------
// Kernel 4: combined weights. Wcb (bf16) [idx][o][c] = lin@pw * aScale[c];
// Bc[idx][o] = (lin@pw)@bShift + lin@pwb.
// R6 changes:
//  - 1D grid 432 with XCD-aware idx mapping: XCD x owns ALL 48 og-blocks of
//    idx=x (pw[x] 590KB stays L2-resident on that XCD); idx=8 spread across
//    XCDs. Before: all 432 blocks co-resident wanted all 9 slices (5.3MB)
//    in every 4MB L2 -> thrash -> L3-latency loads.
//  - m-loop: manual 8x unroll, 8 strided pv loads batched + next batch
//    prefetched before the 64 FMAs (8 loads in flight vs 1).
// FMA order over m unchanged -> bitwise identical results.
// ---------------------------------------------------------------------------
__global__ void k_wcomb(const float* __restrict__ pw, const float* __restrict__ pwb,
                        const float* __restrict__ lin,
                        const float* __restrict__ aScale, const float* __restrict__ bShift,
                        u16* __restrict__ Wcb, float* __restrict__ Bc) {
    __shared__ float red[8];
    int id = blockIdx.x;            // 0..431
    int xcd = id & 7;
    int k2 = id >> 3;               // 0..53
    int idx, og;
    if (k2 < 48) { idx = xcd; og = k2; }
    else         { idx = 8;   og = xcd * 6 + (k2 - 48); }
    int c = threadIdx.x;            // 0..383
    int wave = c >> 6, lane = c & 63;
    int li = (idx < 3) ? idx : 3 + (idx % 3);   // replicate branch-2 lin reuse bug
    float acc[8];
#pragma unroll
    for (int k = 0; k < 8; ++k) acc[k] = 0.f;
    const float* pwm = pw + (idx * C_) * C_ + c;
    const float* lb  = lin + ((li * C_) + og * 8) * C_;

    float pvv[8];
#pragma unroll
    for (int u = 0; u < 8; ++u) pvv[u] = pwm[u * C_];
    for (int m0 = 0; m0 < C_; m0 += 8) {
        float pvn[8];
        if (m0 + 8 < C_) {
#pragma unroll
            for (int u = 0; u < 8; ++u) pvn[u] = pwm[(m0 + 8 + u) * C_];
        } else {
#pragma unroll
            for (int u = 0; u < 8; ++u) pvn[u] = 0.f;
        }
#pragma unroll
        for (int u = 0; u < 8; ++u) {
            float pv = pvv[u];
#pragma unroll
            for (int k = 0; k < 8; ++k)
                acc[k] += lb[k * C_ + (m0 + u)] * pv;
        }
#pragma unroll
        for (int u = 0; u < 8; ++u) pvv[u] = pvn[u];
    }

    float aS = aScale[idx * C_ + c];
    float bS = bShift[idx * C_ + c];
    float pwbc = pwb[idx * C_ + c];
    for (int k = 0; k < 8; ++k) {
        int o = og * 8 + k;
        Wcb[(idx * C_ + o) * C_ + c] = f2bf(acc[k] * aS);
        float v = acc[k] * bS + lin[(li * C_ + o) * C_ + c] * pwbc;
#pragma unroll
        for (int msk = 1; msk < 64; msk <<= 1) v += __shfl_xor(v, msk);
        if (lane == 0) red[wave] = v;
        __syncthreads();
        if (c == 0)
            Bc[idx * C_ + o] = red[0] + red[1] + red[2] + red[3] + red[4] + red[5];
        __syncthreads();
    }
}

// ---------------------------------------------------------------------------
// Kernel 5: MFMA GEMM, m97 structure: 128x128 tile, BK=32, double-buffered
// LDS staged via global_load_lds(16B), 1 barrier per K-step.
// ---------------------------------------------------------------------------
__launch_bounds__(256)
__global__ void k_gemm(const u16* __restrict__ y, const u16* __restrict__ Wcb,
                       const float* __restrict__ Bc, u16* __restrict__ qkv) {
    __shared__ __align__(16) u16 ldsA[2][4096];   // [stage][128 rows][4 chunks*8]
    __shared__ __align__(16) u16 ldsB[2][4096];

    int id = blockIdx.x;            // 0..3023
    int xcd = id & 7;
    int kb = id >> 3;               // 0..377
    int zz = kb / 21;               // 0..17
    int t  = kb % 21;
    int z  = zz * 8 + xcd;          // 0..143
    int by = t / 7, bx = t % 7;
    int idx = z >> 4, b = z & 15;

    int tid = threadIdx.x;
    int wave = tid >> 6;
    int lane = tid & 63;
    int lq = lane & 15;
    int quad = lane >> 4;
    int o_base = by * 128 + (wave & 1) * 64;          // for bias/epilogue
    int s_base_w = bx * 128 + (wave >> 1) * 64;       // for epilogue

    const u16* ybase = y + (size_t)(idx * B_ + b) * S_ * C_;
    const u16* wbase = Wcb + (size_t)idx * C_ * C_;

    // staging geometry: element e = i*256+tid covers 16B; row r=e>>2, chunk q=e&3
    int r0 = tid >> 2;              // issue-0 row (0..63); issue-1 adds 64
    int qs = (tid & 3) ^ ((r0 ^ (r0 >> 2)) & 3);   // swizzle invariant under +64
    int srA0 = bx * 128 + r0;       if (srA0 > S_ - 1) srA0 = S_ - 1;
    int srA1 = bx * 128 + r0 + 64;  if (srA1 > S_ - 1) srA1 = S_ - 1;
    const u16* gA0 = ybase + (size_t)srA0 * C_ + qs * 8;
    const u16* gA1 = ybase + (size_t)srA1 * C_ + qs * 8;
    const u16* gB0 = wbase + (size_t)(by * 128 + r0) * C_ + qs * 8;
    const u16* gB1 = wbase + (size_t)(by * 128 + r0 + 64) * C_ + qs * 8;
    int lo0 = wave * 512;           // u16 idx: wave base, issue 0
    int lo1 = 2048 + wave * 512;    // issue 1

#define STAGE(stg, kk) do {                          \
        gld16(gA0 + (kk) * 32, &ldsA[stg][lo0]);     \
        gld16(gA1 + (kk) * 32, &ldsA[stg][lo1]);     \
        gld16(gB0 + (kk) * 32, &ldsB[stg][lo0]);     \
        gld16(gB1 + (kk) * 32, &ldsB[stg][lo1]);     \
    } while (0)

    f32x4 acc[4][4];
#pragma unroll
    for (int i = 0; i < 4; ++i)
#pragma unroll
        for (int j = 0; j < 4; ++j) acc[i][j] = (f32x4){0.f,0.f,0.f,0.f};

    STAGE(0, 0);
    __syncthreads();

    int qoff = (quad ^ ((lq ^ (lq >> 2)) & 3)) * 8;   // read-side swizzle
    bf16x8 af[4], bw[4];
#pragma unroll
    for (int ks = 0; ks < 12; ++ks) {
        int cur = ks & 1;
        if (ks < 11) STAGE(cur ^ 1, ks + 1);          // async into other buffer
#pragma unroll
        for (int mt = 0; mt < 4; ++mt) {
            int sl = (wave >> 1) * 64 + mt * 16 + lq;
            __builtin_memcpy(&af[mt], &ldsA[cur][sl * 32 + qoff], 16);
        }
#pragma unroll
        for (int nt = 0; nt < 4; ++nt) {
            int ol = (wave & 1) * 64 + nt * 16 + lq;
            __builtin_memcpy(&bw[nt], &ldsB[cur][ol * 32 + qoff], 16);
        }
#pragma unroll
        for (int mt = 0; mt < 4; ++mt)
#pragma unroll
            for (int nt = 0; nt < 4; ++nt)
                acc[mt][nt] = __builtin_amdgcn_mfma_f32_16x16x32_bf16(
                    af[mt], bw[nt], acc[mt][nt], 0, 0, 0);
        __syncthreads();    // drains this step's stage (vmcnt) + frees cur buf
    }
#undef STAGE

    float bias[4];
#pragma unroll
    for (int nt = 0; nt < 4; ++nt) bias[nt] = Bc[idx * C_ + o_base + nt * 16 + lq];
    u16* obase = qkv + ((size_t)(idx * B_ + b) * S_) * C_;
#pragma unroll
    for (int mt = 0; mt < 4; ++mt) {
#pragma unroll
        for (int r = 0; r < 4; ++r) {
            int s = s_base_w + mt * 16 + quad * 4 + r;
            if (s >= S_) continue;
            u16* row = obase + (size_t)s * C_ + o_base + lq;
#pragma unroll
            for (int nt = 0; nt < 4; ++nt)
                row[nt * 16] = f2bf(acc[mt][nt][r] + bias[nt]);
        }
    }
}

// ---------------------------------------------------------------------------
// Kernel 6: MFMA flash attention, M=32/wave, no-max softmax, T=64 chunks.
// R5 structure (packed P, swizzled V b128 reads, exp2, tail split),
// __launch_bounds__(256,4). Unchanged in R6.
// ---------------------------------------------------------------------------
__launch_bounds__(256, 4)
__global__ void k_attn(const u16* __restrict__ qkv, float* __restrict__ out) {
    __shared__ __align__(16) u16 sm[12544];   // V 8192 B @0; P 4*4224 B @8192

    int id = blockIdx.x;
    int g8 = id & 7;
    int rest = id >> 3;             // 0..251
    int qtile = rest % 7;           // 0..6
    int zh = (rest / 7) * 8 + g8;   // 0..287
    int z = zh / 6, h = zh % 6;     // z: br*16+b
    int br = z >> 4;
    int tid = threadIdx.x;
    int wave = tid >> 6;
    int lane = tid & 63;
    int lq = lane & 15;
    int quad = lane >> 4;

    int idxq = 3 * br;
    const u16* qp = qkv + (size_t)((idxq * B_ + (z & 15)) * S_) * C_ + h * HD_;
    const u16* kp = qkv + (size_t)(((idxq + 1) * B_ + (z & 15)) * S_) * C_ + h * HD_;
    const u16* vp = qkv + (size_t)(((idxq + 2) * B_ + (z & 15)) * S_) * C_ + h * HD_;

    int qbase = qtile * 128 + wave * 32;
    int qrA = qbase + lq;      if (qrA > S_ - 1) qrA = S_ - 1;
    int qrB = qbase + 16 + lq; if (qrB > S_ - 1) qrB = S_ - 1;
    const u16* qpa = qp + (size_t)qrA * C_ + quad * 8;
    const u16* qpb = qp + (size_t)qrB * C_ + quad * 8;
    bf16x8 aqA0 = *(const bf16x8*)qpa;
    bf16x8 aqA1 = *(const bf16x8*)(qpa + 32);
    bf16x8 aqB0 = *(const bf16x8*)qpb;
    bf16x8 aqB1 = *(const bf16x8*)(qpb + 32);

    f32x4 oA[4], oB[4];
#pragma unroll
    for (int i = 0; i < 4; ++i) { oA[i] = (f32x4){0.f,0.f,0.f,0.f}; oB[i] = oA[i]; }
    float rsA[4] = {0.f,0.f,0.f,0.f}, rsB[4] = {0.f,0.f,0.f,0.f};

    // V staging: 2 consecutive t, 8 d per thread (256 thr cover 64t x 64d)
    int t2 = (tid & 31) * 2;        // 0..62
    int dg = (tid >> 5) * 8;        // 0..56
    char* smb = (char*)sm;
    // V write addresses: byte = d*128 + ((t2/8 ^ (d&7))<<4) + (t2&7)*2, d=dg+e
    // P buffer (u32 view): per-wave base, rows=q (0..15), stride 66 u32
    u32* pb0 = (u32*)sm + 2048 + wave * 1056;
    u32* pwr = pb0 + (quad * 4) * 66 + lq;       // store base: + r*66 + tt*16
    const u32* prd = pb0 + lq * 66 + quad * 8;   // read base: + n*32 + j
    int sw = lq & 7;                              // V read swizzle key
    int vrb0 = lq * 128 + ((quad ^ sw) << 4);          // kh=0 V-frag byte base
    int vrb1 = lq * 128 + (((4 + quad) ^ sw) << 4);    // kh=1

#define VSTAGE(TG0, TG1) do {                                              \
        bf16x8 v0 = *(const bf16x8*)(vp + (size_t)(TG0) * C_ + dg);        \
        bf16x8 v1 = *(const bf16x8*)(vp + (size_t)(TG1) * C_ + dg);        \
        __syncthreads();                                                   \
        _Pragma("unroll")                                                  \
        for (int e = 0; e < 8; ++e) {                                      \
            u32 pk = (u32)(u16)v0[e] | ((u32)(u16)v1[e] << 16);            \
            *(u32*)(smb + (dg + e) * 128 + ((((t2 >> 3) ^ e)) << 4)        \
                    + ((t2 & 7) << 1)) = pk;                               \
        }                                                                  \
        __syncthreads();                                                   \
    } while (0)

    for (int ch = 0; ch < 12; ++ch) {
        int tc = ch * 64;
        VSTAGE(tc + t2, tc + t2 + 1);

        // ---- QK^T + exp + packed P-store, per 16-t tile (all t live)
#pragma unroll
        for (int tt = 0; tt < 4; ++tt) {
            const u16* kptr = kp + (size_t)(tc + tt * 16 + lq) * C_ + quad * 8;
            bf16x8 bk0 = *(const bf16x8*)kptr;
            bf16x8 bk1 = *(const bf16x8*)(kptr + 32);
            f32x4 sA = {0.f,0.f,0.f,0.f}, sB = sA;
            sA = __builtin_amdgcn_mfma_f32_16x16x32_bf16(aqA0, bk0, sA, 0, 0, 0);
            sA = __builtin_amdgcn_mfma_f32_16x16x32_bf16(aqA1, bk1, sA, 0, 0, 0);
            sB = __builtin_amdgcn_mfma_f32_16x16x32_bf16(aqB0, bk0, sB, 0, 0, 0);
            sB = __builtin_amdgcn_mfma_f32_16x16x32_bf16(aqB1, bk1, sB, 0, 0, 0);
#pragma unroll
            for (int r = 0; r < 4; ++r) {
                float ea = exp2_fast(sA[r] * LSC_);
                float eb = exp2_fast(sB[r] * LSC_);
                u32 ua = __float_as_uint(ea) & 0xFFFF0000u;   // trunc bf16
                u32 ub = __float_as_uint(eb) & 0xFFFF0000u;
                rsA[r] += __uint_as_float(ua);    // consistent w/ numerator
                rsB[r] += __uint_as_float(ub);
                // pk = {eb.hi16, ea.hi16}
                pwr[r * 66 + tt * 16] = __builtin_amdgcn_perm(
                    __float_as_uint(eb), __float_as_uint(ea), 0x07060302u);
            }
        }

        // ---- P A-frags (shared reads, perm unpack; memcpy orders vs stores)
        bf16x8 apA[2], apB[2];
#pragma unroll
        for (int n = 0; n < 2; ++n) {
            u32 uu[8];
            __builtin_memcpy(uu, prd + n * 32, 32);
            union { u32 w[4]; bf16x8 v; } ca, cb;
#pragma unroll
            for (int jj = 0; jj < 4; ++jj) {
                ca.w[jj] = __builtin_amdgcn_perm(uu[2*jj+1], uu[2*jj], 0x05040100u);
                cb.w[jj] = __builtin_amdgcn_perm(uu[2*jj+1], uu[2*jj], 0x07060302u);
            }
            apA[n] = ca.v; apB[n] = cb.v;
        }

        // ---- PV: swizzled aligned b128 V-frags, shared by both rowsets
#pragma unroll
        for (int dt = 0; dt < 4; ++dt) {
            bf16x8 bv0, bv1;
            __builtin_memcpy(&bv0, smb + dt * 2048 + vrb0, 16);
            __builtin_memcpy(&bv1, smb + dt * 2048 + vrb1, 16);
            oA[dt] = __builtin_amdgcn_mfma_f32_16x16x32_bf16(apA[0], bv0, oA[dt], 0, 0, 0);
            oB[dt] = __builtin_amdgcn_mfma_f32_16x16x32_bf16(apB[0], bv0, oB[dt], 0, 0, 0);
            oA[dt] = __builtin_amdgcn_mfma_f32_16x16x32_bf16(apA[1], bv1, oA[dt], 0, 0, 0);
            oB[dt] = __builtin_amdgcn_mfma_f32_16x16x32_bf16(apB[1], bv1, oB[dt], 0, 0, 0);
        }
    }

    // ---- tail chunk: t 768..783 live (16 of 64)
    {
        int tc = 768;
        int tg0 = tc + t2;     if (tg0 > S_ - 1) tg0 = S_ - 1;
        int tg1 = tc + t2 + 1; if (tg1 > S_ - 1) tg1 = S_ - 1;
        VSTAGE(tg0, tg1);

        const u16* kptr = kp + (size_t)(tc + lq) * C_ + quad * 8;
        bf16x8 bk0 = *(const bf16x8*)kptr;
        bf16x8 bk1 = *(const bf16x8*)(kptr + 32);
        f32x4 sA = {0.f,0.f,0.f,0.f}, sB = sA;
        sA = __builtin_amdgcn_mfma_f32_16x16x32_bf16(aqA0, bk0, sA, 0, 0, 0);
        sA = __builtin_amdgcn_mfma_f32_16x16x32_bf16(aqA1, bk1, sA, 0, 0, 0);
        sB = __builtin_amdgcn_mfma_f32_16x16x32_bf16(aqB0, bk0, sB, 0, 0, 0);
        sB = __builtin_amdgcn_mfma_f32_16x16x32_bf16(aqB1, bk1, sB, 0, 0, 0);
#pragma unroll
        for (int r = 0; r < 4; ++r) {
            float ea = exp2_fast(sA[r] * LSC_);
            float eb = exp2_fast(sB[r] * LSC_);
            u32 ua = __float_as_uint(ea) & 0xFFFF0000u;
            u32 ub = __float_as_uint(eb) & 0xFFFF0000u;
            rsA[r] += __uint_as_float(ua);
            rsB[r] += __uint_as_float(ub);
            pwr[r * 66]      = __builtin_amdgcn_perm(
                __float_as_uint(eb), __float_as_uint(ea), 0x07060302u);
            pwr[r * 66 + 16] = 0;               // zero t 16..31 (dead)
        }

        bf16x8 apA0, apB0;
        {
            u32 uu[8];
            __builtin_memcpy(uu, prd, 32);
            union { u32 w[4]; bf16x8 v; } ca, cb;
#pragma unroll
            for (int jj = 0; jj < 4; ++jj) {
                ca.w[jj] = __builtin_amdgcn_perm(uu[2*jj+1], uu[2*jj], 0x05040100u);
                cb.w[jj] = __builtin_amdgcn_perm(uu[2*jj+1], uu[2*jj], 0x07060302u);
            }
            apA0 = ca.v; apB0 = cb.v;
        }
#pragma unroll
        for (int dt = 0; dt < 4; ++dt) {
            bf16x8 bv0;
            __builtin_memcpy(&bv0, smb + dt * 2048 + vrb0, 16);
            oA[dt] = __builtin_amdgcn_mfma_f32_16x16x32_bf16(apA0, bv0, oA[dt], 0, 0, 0);
            oB[dt] = __builtin_amdgcn_mfma_f32_16x16x32_bf16(apB0, bv0, oB[dt], 0, 0, 0);
        }
    }
#undef VSTAGE

    // ---- final l reduction (once, 16-lane row groups)
#pragma unroll
    for (int msk = 1; msk <= 8; msk <<= 1)
#pragma unroll
        for (int r = 0; r < 4; ++r) {
            rsA[r] += __shfl_xor(rsA[r], msk);
            rsB[r] += __shfl_xor(rsB[r], msk);
        }

    // ---- epilogue
    size_t obase = ((size_t)z * NH_ + h) * S_ * HD_;
#pragma unroll
    for (int r = 0; r < 4; ++r) {
        int qa = qbase + quad * 4 + r;
        if (qa < S_) {
            float inv = 1.f / rsA[r];
            float* dst = out + obase + (size_t)qa * HD_ + lq;
            dst[0]  = oA[0][r] * inv;
            dst[16] = oA[1][r] * inv;
            dst[32] = oA[2][r] * inv;
            dst[48] = oA[3][r] * inv;
        }
        int qb = qbase + 16 + quad * 4 + r;
        if (qb < S_) {
            float inv = 1.f / rsB[r];
            float* dst = out + obase + (size_t)qb * HD_ + lq;
            dst[0]  = oB[0][r] * inv;
            dst[16] = oB[1][r] * inv;
            dst[32] = oB[2][r] * inv;
            dst[48] = oB[3][r] * inv;
        }
    }
}

// ---------------------------------------------------------------------------
extern "C" void kernel_launch(void* const* d_in, const int* in_sizes, int n_in,
                              void* d_out, int out_size, void* d_ws, size_t ws_size,
                              hipStream_t stream) {
    (void)in_sizes; (void)n_in; (void)out_size; (void)ws_size;
    const float* x1    = (const float*)d_in[0];
    const float* x2    = (const float*)d_in[3];
    const float* dw    = (const float*)d_in[6];
    const float* gamma = (const float*)d_in[7];
    const float* beta  = (const float*)d_in[8];
    const float* pw    = (const float*)d_in[9];
    const float* pwb   = (const float*)d_in[10];
    const float* lin   = (const float*)d_in[11];
    float* out = (float*)d_out;

    char* ws = (char*)d_ws;
    // ws layout (bytes):
    // y    bf16 [9][16][784][384]  @ 28901376   size 86,704,128
    // qkv  bf16 [9][16][784][384]  @ 115605504  size 86,704,128
    // Wcb  bf16 [9][384][384]      @ 202309632  size 2,654,208
    // Bc   f32  [9][384]           @ 204963840  size 13,824
    // aS   f32  [9][384]           @ 204977664  size 13,824
    // bS   f32  [9][384]           @ 204991488  size 13,824
    // part f32  [9][384][2]        @ 205005312  size 27,648 (memset to 0)
    u16*  y   = (u16*)(ws + 28901376);
    u16*  qkv = (u16*)(ws + 115605504);
    u16*  Wcb = (u16*)(ws + 202309632);
    float* Bc = (float*)(ws + 204963840);
    float* aS = (float*)(ws + 204977664);
    float* bS = (float*)(ws + 204991488);
    float* part = (float*)(ws + 205005312);

    hipMemsetAsync(part, 0, 9 * C_ * 2 * sizeof(float), stream);
    k_conv  <<<dim3(1344), 384, 0, stream>>>(x1, x2, dw, y, part);
    k_stats2<<<dim3(9), 384, 0, stream>>>(part, gamma, beta, aS, bS);
    k_wcomb <<<dim3(432), 384, 0, stream>>>(pw, pwb, lin, aS, bS, Wcb, Bc);
    k_gemm  <<<dim3(3024), 256, 0, stream>>>(y, Wcb, Bc, qkv);
    k_attn  <<<dim3(2016), 256, 0, stream>>>(qkv, out);
}

// Round 7
// 435.918 us; speedup vs baseline: 1.0454x; 1.0454x over previous
//
#include <hip/hip_runtime.h>

typedef unsigned short u16;
typedef unsigned int u32;
typedef unsigned long long u64;

#define B_   16
#define C_   384
#define H_   28
#define W_   28
#define S_   784
#define NH_  6
#define HD_  64
#define BS_  (B_ * S_)            // 12544
#define SCALE_ 0.05103103630798288f  // 384^-0.5
#define LSC_   0.07362225484151387f  // SCALE_ * log2(e): exp(s*SCALE) = 2^(s*LSC)
#define EPS_ 1e-5f

typedef __attribute__((ext_vector_type(8))) short bf16x8;
typedef __attribute__((ext_vector_type(4))) float f32x4;

__device__ __forceinline__ float bf2f(u16 u) {
    return __uint_as_float(((u32)u) << 16);
}
__device__ __forceinline__ u16 f2bf(float f) {
    u32 x = __float_as_uint(f);
    u32 r = (x + 0x7fffu + ((x >> 16) & 1u)) >> 16;   // RNE
    return (u16)r;
}

// async global->LDS 16B per lane; dest = wave-uniform base + lane*16 (HW rule)
__device__ __forceinline__ void gld16(const u16* g, u16* l) {
    __builtin_amdgcn_global_load_lds(
        (__attribute__((address_space(1))) void*)g,
        (__attribute__((address_space(3))) void*)l, 16, 0, 0);
}

__device__ __forceinline__ float exp2_fast(float x) {
    float r;
    asm("v_exp_f32 %0, %1" : "=v"(r) : "v"(x));
    return r;
}

// ---------------------------------------------------------------------------
// Kernel 2 (fused, 3-in-1 by input group): depthwise 3x3 conv.
// R7: back to the ROLLED w-loop (R6's full unroll + ring regressed: 6-wave
// blocks packed only ~4/CU -> 15% occupancy drain tail). TLP instead of ILP:
// 128-thread blocks (c-chunk of 128), grid 4032 -> ~14 blocks/CU capacity,
// 3x finer dispatch granularity. Same XCD/halo swizzle; cc innermost.
// ---------------------------------------------------------------------------
__launch_bounds__(128)
__global__ void k_conv(const float* __restrict__ x1, const float* __restrict__ x2,
                       const float* __restrict__ dw, u16* __restrict__ y,
                       float* __restrict__ part) {
    int id = blockIdx.x;            // 0..4031
    int xcd = id & 7;
    int r = id >> 3;                // 0..503
    int cc = r % 3;
    int rr = r / 3;                 // 0..167
    int p = xcd + 8 * (rr / 28);    // 0..47
    int h = rr % 28;                // 0..27
    int g = p / 16;                 // input group (wave-uniform)
    int b = p % 16;
    int c = cc * 128 + threadIdx.x; // 0..383

    const float* pa = x1 + (size_t)b * S_ * C_ + c;
    const float* pb = x2 + (size_t)b * S_ * C_ + c;

    float wt[3][9];
#pragma unroll
    for (int i = 0; i < 3; ++i)
#pragma unroll
        for (int t = 0; t < 9; ++t)
            wt[i][t] = dw[((3 * g + i) * C_ + c) * 9 + t];

    // sliding window of the selected input (sum formed at load for g=2)
    float a[3][3];
#pragma unroll
    for (int dh = 0; dh < 3; ++dh) {
        int hh = h + dh - 1;
        bool hv = (hh >= 0) && (hh < H_);
        size_t o1 = (size_t)(hh * W_ + 0) * C_;
        size_t o2 = (size_t)(hh * W_ + 1) * C_;
        float v1 = 0.f, v2 = 0.f;
        if (hv) {
            if (g == 0)      { v1 = pa[o1];           v2 = pa[o2]; }
            else if (g == 1) { v1 = pb[o1];           v2 = pb[o2]; }
            else             { v1 = pa[o1] + pb[o1];  v2 = pa[o2] + pb[o2]; }
        }
        a[dh][0] = 0.f; a[dh][1] = v1; a[dh][2] = v2;
    }

    u16* dst[3];
#pragma unroll
    for (int i = 0; i < 3; ++i)
        dst[i] = y + ((size_t)((3 * g + i) * B_ + b) * S_ + h * W_) * C_ + c;

    float sum[3] = {0.f, 0.f, 0.f}, sq[3] = {0.f, 0.f, 0.f};

    for (int w = 0; w < W_; ++w) {
#pragma unroll
        for (int i = 0; i < 3; ++i) {
            const float* W9 = wt[i];
            float acc = a[0][0]*W9[0] + a[0][1]*W9[1] + a[0][2]*W9[2]
                      + a[1][0]*W9[3] + a[1][1]*W9[4] + a[1][2]*W9[5]
                      + a[2][0]*W9[6] + a[2][1]*W9[7] + a[2][2]*W9[8];
            sum[i] += acc;
            sq[i] = fmaf(acc, acc, sq[i]);
            dst[i][w * C_] = f2bf(acc);
        }
        // slide + prefetch next column (consumed next iteration)
        int wn = w + 2;
        bool wv = (wn < W_);
#pragma unroll
        for (int dh = 0; dh < 3; ++dh) {
            a[dh][0] = a[dh][1];
            a[dh][1] = a[dh][2];
            int hh = h + dh - 1;
            float v = 0.f;
            if (wv && hh >= 0 && hh < H_) {
                size_t off = (size_t)(hh * W_ + wn) * C_;
                if (g == 0)      v = pa[off];
                else if (g == 1) v = pb[off];
                else             v = pa[off] + pb[off];
            }
            a[dh][2] = v;
        }
    }
#pragma unroll
    for (int i = 0; i < 3; ++i) {
        atomicAdd(&part[((3 * g + i) * C_ + c) * 2],     sum[i]);
        atomicAdd(&part[((3 * g + i) * C_ + c) * 2 + 1], sq[i]);
    }
}

// ---------------------------------------------------------------------------
// Kernel 4: combined weights. Wcb (bf16) [idx][o][c] = lin@pw * aScale[c];
// Bc[idx][o] = (lin@pw)@bShift + lin@pwb.
// R7: k_stats2 folded into the prologue (identical FP sequence, one fewer
// launch). XCD-aware idx mapping + 8x m-unroll with batched pv prefetch
// kept from R6.
// ---------------------------------------------------------------------------
__global__ void k_wcomb(const float* __restrict__ pw, const float* __restrict__ pwb,
                        const float* __restrict__ lin,
                        const float* __restrict__ part,
                        const float* __restrict__ gamma, const float* __restrict__ beta,
                        u16* __restrict__ Wcb, float* __restrict__ Bc) {
    __shared__ float red[8];
    int id = blockIdx.x;            // 0..431
    int xcd = id & 7;
    int k2 = id >> 3;               // 0..53
    int idx, og;
    if (k2 < 48) { idx = xcd; og = k2; }
    else         { idx = 8;   og = xcd * 6 + (k2 - 48); }
    int c = threadIdx.x;            // 0..383
    int wave = c >> 6, lane = c & 63;
    int li = (idx < 3) ? idx : 3 + (idx % 3);   // replicate branch-2 lin reuse bug

    // inline BN finalize (was k_stats2; same op order -> identical results)
    float s_ = part[(idx * C_ + c) * 2];
    float q_ = part[(idx * C_ + c) * 2 + 1];
    float mean = s_ / (float)BS_;
    float var  = q_ / (float)BS_ - mean * mean;
    float aS = gamma[idx * C_ + c] * rsqrtf(var + EPS_);
    float bS = beta[idx * C_ + c] - mean * aS;

    float acc[8];
#pragma unroll
    for (int k = 0; k < 8; ++k) acc[k] = 0.f;
    const float* pwm = pw + (idx * C_) * C_ + c;
    const float* lb  = lin + ((li * C_) + og * 8) * C_;

    float pvv[8];
#pragma unroll
    for (int u = 0; u < 8; ++u) pvv[u] = pwm[u * C_];
    for (int m0 = 0; m0 < C_; m0 += 8) {
        float pvn[8];
        if (m0 + 8 < C_) {
#pragma unroll
            for (int u = 0; u < 8; ++u) pvn[u] = pwm[(m0 + 8 + u) * C_];
        } else {
#pragma unroll
            for (int u = 0; u < 8; ++u) pvn[u] = 0.f;
        }
#pragma unroll
        for (int u = 0; u < 8; ++u) {
            float pv = pvv[u];
#pragma unroll
            for (int k = 0; k < 8; ++k)
                acc[k] += lb[k * C_ + (m0 + u)] * pv;
        }
#pragma unroll
        for (int u = 0; u < 8; ++u) pvv[u] = pvn[u];
    }

    float pwbc = pwb[idx * C_ + c];
    for (int k = 0; k < 8; ++k) {
        int o = og * 8 + k;
        Wcb[(idx * C_ + o) * C_ + c] = f2bf(acc[k] * aS);
        float v = acc[k] * bS + lin[(li * C_ + o) * C_ + c] * pwbc;
#pragma unroll
        for (int msk = 1; msk < 64; msk <<= 1) v += __shfl_xor(v, msk);
        if (lane == 0) red[wave] = v;
        __syncthreads();
        if (c == 0)
            Bc[idx * C_ + o] = red[0] + red[1] + red[2] + red[3] + red[4] + red[5];
        __syncthreads();
    }
}

// ---------------------------------------------------------------------------
// Kernel 5: MFMA GEMM, m97 structure: 128x128 tile, BK=32, double-buffered
// LDS staged via global_load_lds(16B), 1 barrier per K-step.
// ---------------------------------------------------------------------------
__launch_bounds__(256)
__global__ void k_gemm(const u16* __restrict__ y, const u16* __restrict__ Wcb,
                       const float* __restrict__ Bc, u16* __restrict__ qkv) {
    __shared__ __align__(16) u16 ldsA[2][4096];   // [stage][128 rows][4 chunks*8]
    __shared__ __align__(16) u16 ldsB[2][4096];

    int id = blockIdx.x;            // 0..3023
    int xcd = id & 7;
    int kb = id >> 3;               // 0..377
    int zz = kb / 21;               // 0..17
    int t  = kb % 21;
    int z  = zz * 8 + xcd;          // 0..143
    int by = t / 7, bx = t % 7;
    int idx = z >> 4, b = z & 15;

    int tid = threadIdx.x;
    int wave = tid >> 6;
    int lane = tid & 63;
    int lq = lane & 15;
    int quad = lane >> 4;
    int o_base = by * 128 + (wave & 1) * 64;          // for bias/epilogue
    int s_base_w = bx * 128 + (wave >> 1) * 64;       // for epilogue

    const u16* ybase = y + (size_t)(idx * B_ + b) * S_ * C_;
    const u16* wbase = Wcb + (size_t)idx * C_ * C_;

    // staging geometry: element e = i*256+tid covers 16B; row r=e>>2, chunk q=e&3
    int r0 = tid >> 2;              // issue-0 row (0..63); issue-1 adds 64
    int qs = (tid & 3) ^ ((r0 ^ (r0 >> 2)) & 3);   // swizzle invariant under +64
    int srA0 = bx * 128 + r0;       if (srA0 > S_ - 1) srA0 = S_ - 1;
    int srA1 = bx * 128 + r0 + 64;  if (srA1 > S_ - 1) srA1 = S_ - 1;
    const u16* gA0 = ybase + (size_t)srA0 * C_ + qs * 8;
    const u16* gA1 = ybase + (size_t)srA1 * C_ + qs * 8;
    const u16* gB0 = wbase + (size_t)(by * 128 + r0) * C_ + qs * 8;
    const u16* gB1 = wbase + (size_t)(by * 128 + r0 + 64) * C_ + qs * 8;
    int lo0 = wave * 512;           // u16 idx: wave base, issue 0
    int lo1 = 2048 + wave * 512;    // issue 1

#define STAGE(stg, kk) do {                          \
        gld16(gA0 + (kk) * 32, &ldsA[stg][lo0]);     \
        gld16(gA1 + (kk) * 32, &ldsA[stg][lo1]);     \
        gld16(gB0 + (kk) * 32, &ldsB[stg][lo0]);     \
        gld16(gB1 + (kk) * 32, &ldsB[stg][lo1]);     \
    } while (0)

    f32x4 acc[4][4];
#pragma unroll
    for (int i = 0; i < 4; ++i)
#pragma unroll
        for (int j = 0; j < 4; ++j) acc[i][j] = (f32x4){0.f,0.f,0.f,0.f};

    STAGE(0, 0);
    __syncthreads();

    int qoff = (quad ^ ((lq ^ (lq >> 2)) & 3)) * 8;   // read-side swizzle
    bf16x8 af[4], bw[4];
#pragma unroll
    for (int ks = 0; ks < 12; ++ks) {
        int cur = ks & 1;
        if (ks < 11) STAGE(cur ^ 1, ks + 1);          // async into other buffer
#pragma unroll
        for (int mt = 0; mt < 4; ++mt) {
            int sl = (wave >> 1) * 64 + mt * 16 + lq;
            __builtin_memcpy(&af[mt], &ldsA[cur][sl * 32 + qoff], 16);
        }
#pragma unroll
        for (int nt = 0; nt < 4; ++nt) {
            int ol = (wave & 1) * 64 + nt * 16 + lq;
            __builtin_memcpy(&bw[nt], &ldsB[cur][ol * 32 + qoff], 16);
        }
#pragma unroll
        for (int mt = 0; mt < 4; ++mt)
#pragma unroll
            for (int nt = 0; nt < 4; ++nt)
                acc[mt][nt] = __builtin_amdgcn_mfma_f32_16x16x32_bf16(
                    af[mt], bw[nt], acc[mt][nt], 0, 0, 0);
        __syncthreads();    // drains this step's stage (vmcnt) + frees cur buf
    }
#undef STAGE

    float bias[4];
#pragma unroll
    for (int nt = 0; nt < 4; ++nt) bias[nt] = Bc[idx * C_ + o_base + nt * 16 + lq];
    u16* obase = qkv + ((size_t)(idx * B_ + b) * S_) * C_;
#pragma unroll
    for (int mt = 0; mt < 4; ++mt) {
#pragma unroll
        for (int r = 0; r < 4; ++r) {
            int s = s_base_w + mt * 16 + quad * 4 + r;
            if (s >= S_) continue;
            u16* row = obase + (size_t)s * C_ + o_base + lq;
#pragma unroll
            for (int nt = 0; nt < 4; ++nt)
                row[nt * 16] = f2bf(acc[mt][nt][r] + bias[nt]);
        }
    }
}

// ---------------------------------------------------------------------------
// Kernel 6: MFMA flash attention, M=32/wave, no-max softmax, T=64 chunks.
// R5 structure (packed P, swizzled V b128 reads, exp2, tail split),
// __launch_bounds__(256,4). Unchanged.
// ---------------------------------------------------------------------------
__launch_bounds__(256, 4)
__global__ void k_attn(const u16* __restrict__ qkv, float* __restrict__ out) {
    __shared__ __align__(16) u16 sm[12544];   // V 8192 B @0; P 4*4224 B @8192

    int id = blockIdx.x;
    int g8 = id & 7;
    int rest = id >> 3;             // 0..251
    int qtile = rest % 7;           // 0..6
    int zh = (rest / 7) * 8 + g8;   // 0..287
    int z = zh / 6, h = zh % 6;     // z: br*16+b
    int br = z >> 4;
    int tid = threadIdx.x;
    int wave = tid >> 6;
    int lane = tid & 63;
    int lq = lane & 15;
    int quad = lane >> 4;

    int idxq = 3 * br;
    const u16* qp = qkv + (size_t)((idxq * B_ + (z & 15)) * S_) * C_ + h * HD_;
    const u16* kp = qkv + (size_t)(((idxq + 1) * B_ + (z & 15)) * S_) * C_ + h * HD_;
    const u16* vp = qkv + (size_t)(((idxq + 2) * B_ + (z & 15)) * S_) * C_ + h * HD_;

    int qbase = qtile * 128 + wave * 32;
    int qrA = qbase + lq;      if (qrA > S_ - 1) qrA = S_ - 1;
    int qrB = qbase + 16 + lq; if (qrB > S_ - 1) qrB = S_ - 1;
    const u16* qpa = qp + (size_t)qrA * C_ + quad * 8;
    const u16* qpb = qp + (size_t)qrB * C_ + quad * 8;
    bf16x8 aqA0 = *(const bf16x8*)qpa;
    bf16x8 aqA1 = *(const bf16x8*)(qpa + 32);
    bf16x8 aqB0 = *(const bf16x8*)qpb;
    bf16x8 aqB1 = *(const bf16x8*)(qpb + 32);

    f32x4 oA[4], oB[4];
#pragma unroll
    for (int i = 0; i < 4; ++i) { oA[i] = (f32x4){0.f,0.f,0.f,0.f}; oB[i] = oA[i]; }
    float rsA[4] = {0.f,0.f,0.f,0.f}, rsB[4] = {0.f,0.f,0.f,0.f};

    // V staging: 2 consecutive t, 8 d per thread (256 thr cover 64t x 64d)
    int t2 = (tid & 31) * 2;        // 0..62
    int dg = (tid >> 5) * 8;        // 0..56
    char* smb = (char*)sm;
    // V write addresses: byte = d*128 + ((t2/8 ^ (d&7))<<4) + (t2&7)*2, d=dg+e
    // P buffer (u32 view): per-wave base, rows=q (0..15), stride 66 u32
    u32* pb0 = (u32*)sm + 2048 + wave * 1056;
    u32* pwr = pb0 + (quad * 4) * 66 + lq;       // store base: + r*66 + tt*16
    const u32* prd = pb0 + lq * 66 + quad * 8;   // read base: + n*32 + j
    int sw = lq & 7;                              // V read swizzle key
    int vrb0 = lq * 128 + ((quad ^ sw) << 4);          // kh=0 V-frag byte base
    int vrb1 = lq * 128 + (((4 + quad) ^ sw) << 4);    // kh=1

#define VSTAGE(TG0, TG1) do {                                              \
        bf16x8 v0 = *(const bf16x8*)(vp + (size_t)(TG0) * C_ + dg);        \
        bf16x8 v1 = *(const bf16x8*)(vp + (size_t)(TG1) * C_ + dg);        \
        __syncthreads();                                                   \
        _Pragma("unroll")                                                  \
        for (int e = 0; e < 8; ++e) {                                      \
            u32 pk = (u32)(u16)v0[e] | ((u32)(u16)v1[e] << 16);            \
            *(u32*)(smb + (dg + e) * 128 + ((((t2 >> 3) ^ e)) << 4)        \
                    + ((t2 & 7) << 1)) = pk;                               \
        }                                                                  \
        __syncthreads();                                                   \
    } while (0)

    for (int ch = 0; ch < 12; ++ch) {
        int tc = ch * 64;
        VSTAGE(tc + t2, tc + t2 + 1);

        // ---- QK^T + exp + packed P-store, per 16-t tile (all t live)
#pragma unroll
        for (int tt = 0; tt < 4; ++tt) {
            const u16* kptr = kp + (size_t)(tc + tt * 16 + lq) * C_ + quad * 8;
            bf16x8 bk0 = *(const bf16x8*)kptr;
            bf16x8 bk1 = *(const bf16x8*)(kptr + 32);
            f32x4 sA = {0.f,0.f,0.f,0.f}, sB = sA;
            sA = __builtin_amdgcn_mfma_f32_16x16x32_bf16(aqA0, bk0, sA, 0, 0, 0);
            sA = __builtin_amdgcn_mfma_f32_16x16x32_bf16(aqA1, bk1, sA, 0, 0, 0);
            sB = __builtin_amdgcn_mfma_f32_16x16x32_bf16(aqB0, bk0, sB, 0, 0, 0);
            sB = __builtin_amdgcn_mfma_f32_16x16x32_bf16(aqB1, bk1, sB, 0, 0, 0);
#pragma unroll
            for (int r = 0; r < 4; ++r) {
                float ea = exp2_fast(sA[r] * LSC_);
                float eb = exp2_fast(sB[r] * LSC_);
                u32 ua = __float_as_uint(ea) & 0xFFFF0000u;   // trunc bf16
                u32 ub = __float_as_uint(eb) & 0xFFFF0000u;
                rsA[r] += __uint_as_float(ua);    // consistent w/ numerator
                rsB[r] += __uint_as_float(ub);
                // pk = {eb.hi16, ea.hi16}
                pwr[r * 66 + tt * 16] = __builtin_amdgcn_perm(
                    __float_as_uint(eb), __float_as_uint(ea), 0x07060302u);
            }
        }

        // ---- P A-frags (shared reads, perm unpack; memcpy orders vs stores)
        bf16x8 apA[2], apB[2];
#pragma unroll
        for (int n = 0; n < 2; ++n) {
            u32 uu[8];
            __builtin_memcpy(uu, prd + n * 32, 32);
            union { u32 w[4]; bf16x8 v; } ca, cb;
#pragma unroll
            for (int jj = 0; jj < 4; ++jj) {
                ca.w[jj] = __builtin_amdgcn_perm(uu[2*jj+1], uu[2*jj], 0x05040100u);
                cb.w[jj] = __builtin_amdgcn_perm(uu[2*jj+1], uu[2*jj], 0x07060302u);
            }
            apA[n] = ca.v; apB[n] = cb.v;
        }

        // ---- PV: swizzled aligned b128 V-frags, shared by both rowsets
#pragma unroll
        for (int dt = 0; dt < 4; ++dt) {
            bf16x8 bv0, bv1;
            __builtin_memcpy(&bv0, smb + dt * 2048 + vrb0, 16);
            __builtin_memcpy(&bv1, smb + dt * 2048 + vrb1, 16);
            oA[dt] = __builtin_amdgcn_mfma_f32_16x16x32_bf16(apA[0], bv0, oA[dt], 0, 0, 0);
            oB[dt] = __builtin_amdgcn_mfma_f32_16x16x32_bf16(apB[0], bv0, oB[dt], 0, 0, 0);
            oA[dt] = __builtin_amdgcn_mfma_f32_16x16x32_bf16(apA[1], bv1, oA[dt], 0, 0, 0);
            oB[dt] = __builtin_amdgcn_mfma_f32_16x16x32_bf16(apB[1], bv1, oB[dt], 0, 0, 0);
        }
    }

    // ---- tail chunk: t 768..783 live (16 of 64)
    {
        int tc = 768;
        int tg0 = tc + t2;     if (tg0 > S_ - 1) tg0 = S_ - 1;
        int tg1 = tc + t2 + 1; if (tg1 > S_ - 1) tg1 = S_ - 1;
        VSTAGE(tg0, tg1);

        const u16* kptr = kp + (size_t)(tc + lq) * C_ + quad * 8;
        bf16x8 bk0 = *(const bf16x8*)kptr;
        bf16x8 bk1 = *(const bf16x8*)(kptr + 32);
        f32x4 sA = {0.f,0.f,0.f,0.f}, sB = sA;
        sA = __builtin_amdgcn_mfma_f32_16x16x32_bf16(aqA0, bk0, sA, 0, 0, 0);
        sA = __builtin_amdgcn_mfma_f32_16x16x32_bf16(aqA1, bk1, sA, 0, 0, 0);
        sB = __builtin_amdgcn_mfma_f32_16x16x32_bf16(aqB0, bk0, sB, 0, 0, 0);
        sB = __builtin_amdgcn_mfma_f32_16x16x32_bf16(aqB1, bk1, sB, 0, 0, 0);
#pragma unroll
        for (int r = 0; r < 4; ++r) {
            float ea = exp2_fast(sA[r] * LSC_);
            float eb = exp2_fast(sB[r] * LSC_);
            u32 ua = __float_as_uint(ea) & 0xFFFF0000u;
            u32 ub = __float_as_uint(eb) & 0xFFFF0000u;
            rsA[r] += __uint_as_float(ua);
            rsB[r] += __uint_as_float(ub);
            pwr[r * 66]      = __builtin_amdgcn_perm(
                __float_as_uint(eb), __float_as_uint(ea), 0x07060302u);
            pwr[r * 66 + 16] = 0;               // zero t 16..31 (dead)
        }

        bf16x8 apA0, apB0;
        {
            u32 uu[8];
            __builtin_memcpy(uu, prd, 32);
            union { u32 w[4]; bf16x8 v; } ca, cb;
#pragma unroll
            for (int jj = 0; jj < 4; ++jj) {
                ca.w[jj] = __builtin_amdgcn_perm(uu[2*jj+1], uu[2*jj], 0x05040100u);
                cb.w[jj] = __builtin_amdgcn_perm(uu[2*jj+1], uu[2*jj], 0x07060302u);
            }
            apA0 = ca.v; apB0 = cb.v;
        }
#pragma unroll
        for (int dt = 0; dt < 4; ++dt) {
            bf16x8 bv0;
            __builtin_memcpy(&bv0, smb + dt * 2048 + vrb0, 16);
            oA[dt] = __builtin_amdgcn_mfma_f32_16x16x32_bf16(apA0, bv0, oA[dt], 0, 0, 0);
            oB[dt] = __builtin_amdgcn_mfma_f32_16x16x32_bf16(apB0, bv0, oB[dt], 0, 0, 0);
        }
    }
#undef VSTAGE

    // ---- final l reduction (once, 16-lane row groups)
#pragma unroll
    for (int msk = 1; msk <= 8; msk <<= 1)
#pragma unroll
        for (int r = 0; r < 4; ++r) {
            rsA[r] += __shfl_xor(rsA[r], msk);
            rsB[r] += __shfl_xor(rsB[r], msk);
        }

    // ---- epilogue
    size_t obase = ((size_t)z * NH_ + h) * S_ * HD_;
#pragma unroll
    for (int r = 0; r < 4; ++r) {
        int qa = qbase + quad * 4 + r;
        if (qa < S_) {
            float inv = 1.f / rsA[r];
            float* dst = out + obase + (size_t)qa * HD_ + lq;
            dst[0]  = oA[0][r] * inv;
            dst[16] = oA[1][r] * inv;
            dst[32] = oA[2][r] * inv;
            dst[48] = oA[3][r] * inv;
        }
        int qb = qbase + 16 + quad * 4 + r;
        if (qb < S_) {
            float inv = 1.f / rsB[r];
            float* dst = out + obase + (size_t)qb * HD_ + lq;
            dst[0]  = oB[0][r] * inv;
            dst[16] = oB[1][r] * inv;
            dst[32] = oB[2][r] * inv;
            dst[48] = oB[3][r] * inv;
        }
    }
}

// ---------------------------------------------------------------------------
extern "C" void kernel_launch(void* const* d_in, const int* in_sizes, int n_in,
                              void* d_out, int out_size, void* d_ws, size_t ws_size,
                              hipStream_t stream) {
    (void)in_sizes; (void)n_in; (void)out_size; (void)ws_size;
    const float* x1    = (const float*)d_in[0];
    const float* x2    = (const float*)d_in[3];
    const float* dw    = (const float*)d_in[6];
    const float* gamma = (const float*)d_in[7];
    const float* beta  = (const float*)d_in[8];
    const float* pw    = (const float*)d_in[9];
    const float* pwb   = (const float*)d_in[10];
    const float* lin   = (const float*)d_in[11];
    float* out = (float*)d_out;

    char* ws = (char*)d_ws;
    // ws layout (bytes):
    // y    bf16 [9][16][784][384]  @ 28901376   size 86,704,128
    // qkv  bf16 [9][16][784][384]  @ 115605504  size 86,704,128
    // Wcb  bf16 [9][384][384]      @ 202309632  size 2,654,208
    // Bc   f32  [9][384]           @ 204963840  size 13,824
    // part f32  [9][384][2]        @ 205005312  size 27,648 (memset to 0)
    u16*  y   = (u16*)(ws + 28901376);
    u16*  qkv = (u16*)(ws + 115605504);
    u16*  Wcb = (u16*)(ws + 202309632);
    float* Bc = (float*)(ws + 204963840);
    float* part = (float*)(ws + 205005312);

    hipMemsetAsync(part, 0, 9 * C_ * 2 * sizeof(float), stream);
    k_conv  <<<dim3(4032), 128, 0, stream>>>(x1, x2, dw, y, part);
    k_wcomb <<<dim3(432), 384, 0, stream>>>(pw, pwb, lin, part, gamma, beta, Wcb, Bc);
    k_gemm  <<<dim3(3024), 256, 0, stream>>>(y, Wcb, Bc, qkv);
    k_attn  <<<dim3(2016), 256, 0, stream>>>(qkv, out);
}

// Round 8
// 427.160 us; speedup vs baseline: 1.0668x; 1.0205x over previous
//
#include <hip/hip_runtime.h>

typedef unsigned short u16;
typedef unsigned int u32;
typedef unsigned long long u64;

#define B_   16
#define C_   384
#define H_   28
#define W_   28
#define S_   784
#define NH_  6
#define HD_  64
#define BS_  (B_ * S_)            // 12544
#define SCALE_ 0.05103103630798288f  // 384^-0.5
#define LSC_   0.07362225484151387f  // SCALE_ * log2(e): exp(s*SCALE) = 2^(s*LSC)
#define EPS_ 1e-5f

typedef __attribute__((ext_vector_type(8))) short bf16x8;
typedef __attribute__((ext_vector_type(4))) float f32x4;

__device__ __forceinline__ float bf2f(u16 u) {
    return __uint_as_float(((u32)u) << 16);
}
__device__ __forceinline__ u16 f2bf(float f) {
    u32 x = __float_as_uint(f);
    u32 r = (x + 0x7fffu + ((x >> 16) & 1u)) >> 16;   // RNE
    return (u16)r;
}

// async global->LDS 16B per lane; dest = wave-uniform base + lane*16 (HW rule)
__device__ __forceinline__ void gld16(const u16* g, u16* l) {
    __builtin_amdgcn_global_load_lds(
        (__attribute__((address_space(1))) void*)g,
        (__attribute__((address_space(3))) void*)l, 16, 0, 0);
}

__device__ __forceinline__ float exp2_fast(float x) {
    float r;
    asm("v_exp_f32 %0, %1" : "=v"(r) : "v"(x));
    return r;
}

// ---------------------------------------------------------------------------
// Kernel 2 (fused, 3-in-1 by input group): depthwise 3x3 conv.
// R8: LOADS BEFORE STORES. vmcnt is an in-order queue shared by loads and
// stores: the old loop issued 3 stores then 3 loads per iter, so the next
// iter's load-wait also drained all older stores (~store latency exposed
// every iteration -- why both R6 ILP and R7 TLP were neutral). Now the
// next column's 3 loads issue at the TOP of the iteration, before the
// stores; unroll 4 turns the ring slide into register renaming.
// ---------------------------------------------------------------------------
__launch_bounds__(128)
__global__ void k_conv(const float* __restrict__ x1, const float* __restrict__ x2,
                       const float* __restrict__ dw, u16* __restrict__ y,
                       float* __restrict__ part) {
    int id = blockIdx.x;            // 0..4031
    int xcd = id & 7;
    int r = id >> 3;                // 0..503
    int cc = r % 3;
    int rr = r / 3;                 // 0..167
    int p = xcd + 8 * (rr / 28);    // 0..47
    int h = rr % 28;                // 0..27
    int g = p / 16;                 // input group (wave-uniform)
    int b = p % 16;
    int c = cc * 128 + threadIdx.x; // 0..383

    const float* pa = x1 + (size_t)b * S_ * C_ + c;
    const float* pb = x2 + (size_t)b * S_ * C_ + c;

    float wt[3][9];
#pragma unroll
    for (int i = 0; i < 3; ++i)
#pragma unroll
        for (int t = 0; t < 9; ++t)
            wt[i][t] = dw[((3 * g + i) * C_ + c) * 9 + t];

    // sliding window of the selected input (sum formed at load for g=2)
    float a[3][3];
#pragma unroll
    for (int dh = 0; dh < 3; ++dh) {
        int hh = h + dh - 1;
        bool hv = (hh >= 0) && (hh < H_);
        size_t o1 = (size_t)(hh * W_ + 0) * C_;
        size_t o2 = (size_t)(hh * W_ + 1) * C_;
        float v1 = 0.f, v2 = 0.f;
        if (hv) {
            if (g == 0)      { v1 = pa[o1];           v2 = pa[o2]; }
            else if (g == 1) { v1 = pb[o1];           v2 = pb[o2]; }
            else             { v1 = pa[o1] + pb[o1];  v2 = pa[o2] + pb[o2]; }
        }
        a[dh][0] = 0.f; a[dh][1] = v1; a[dh][2] = v2;
    }

    u16* dst[3];
#pragma unroll
    for (int i = 0; i < 3; ++i)
        dst[i] = y + ((size_t)((3 * g + i) * B_ + b) * S_ + h * W_) * C_ + c;

    float sum[3] = {0.f, 0.f, 0.f}, sq[3] = {0.f, 0.f, 0.f};

#pragma unroll 4
    for (int w = 0; w < W_; ++w) {
        // ---- loads FIRST (next column, consumed next iteration)
        int wn = w + 2;
        bool wv = (wn < W_);
        float nx[3];
#pragma unroll
        for (int dh = 0; dh < 3; ++dh) {
            int hh = h + dh - 1;
            float v = 0.f;
            if (wv && hh >= 0 && hh < H_) {
                size_t off = (size_t)(hh * W_ + wn) * C_;
                if (g == 0)      v = pa[off];
                else if (g == 1) v = pb[off];
                else             v = pa[off] + pb[off];
            }
            nx[dh] = v;
        }
        // ---- compute + stores (after the loads are in the queue)
#pragma unroll
        for (int i = 0; i < 3; ++i) {
            const float* W9 = wt[i];
            float acc = a[0][0]*W9[0] + a[0][1]*W9[1] + a[0][2]*W9[2]
                      + a[1][0]*W9[3] + a[1][1]*W9[4] + a[1][2]*W9[5]
                      + a[2][0]*W9[6] + a[2][1]*W9[7] + a[2][2]*W9[8];
            sum[i] += acc;
            sq[i] = fmaf(acc, acc, sq[i]);
            dst[i][w * C_] = f2bf(acc);
        }
        // ---- slide (renamed away by unroll)
#pragma unroll
        for (int dh = 0; dh < 3; ++dh) {
            a[dh][0] = a[dh][1];
            a[dh][1] = a[dh][2];
            a[dh][2] = nx[dh];
        }
    }
#pragma unroll
    for (int i = 0; i < 3; ++i) {
        atomicAdd(&part[((3 * g + i) * C_ + c) * 2],     sum[i]);
        atomicAdd(&part[((3 * g + i) * C_ + c) * 2 + 1], sq[i]);
    }
}

// ---------------------------------------------------------------------------
// Kernel 4: combined weights. Wcb (bf16) [idx][o][c] = lin@pw * aScale[c];
// Bc[idx][o] = (lin@pw)@bShift + lin@pwb.
// R8: og split 48 -> 96 blocks/idx (4 outputs each): grid 864 (3.4/CU vs
// 1.7/CU -- the 432-grid left ~80 CUs idle in dispatch round 2). FMA order
// over m per output unchanged -> bitwise identical. BN finalize inlined.
// ---------------------------------------------------------------------------
__global__ void k_wcomb(const float* __restrict__ pw, const float* __restrict__ pwb,
                        const float* __restrict__ lin,
                        const float* __restrict__ part,
                        const float* __restrict__ gamma, const float* __restrict__ beta,
                        u16* __restrict__ Wcb, float* __restrict__ Bc) {
    __shared__ float red[8];
    int id = blockIdx.x;            // 0..863
    int xcd = id & 7;
    int k2 = id >> 3;               // 0..107
    int idx, og;
    if (k2 < 96) { idx = xcd; og = k2; }
    else         { idx = 8;   og = xcd * 12 + (k2 - 96); }
    int c = threadIdx.x;            // 0..383
    int wave = c >> 6, lane = c & 63;
    int li = (idx < 3) ? idx : 3 + (idx % 3);   // replicate branch-2 lin reuse bug

    // inline BN finalize (same op order as old k_stats2)
    float s_ = part[(idx * C_ + c) * 2];
    float q_ = part[(idx * C_ + c) * 2 + 1];
    float mean = s_ / (float)BS_;
    float var  = q_ / (float)BS_ - mean * mean;
    float aS = gamma[idx * C_ + c] * rsqrtf(var + EPS_);
    float bS = beta[idx * C_ + c] - mean * aS;

    float acc[4];
#pragma unroll
    for (int k = 0; k < 4; ++k) acc[k] = 0.f;
    const float* pwm = pw + (idx * C_) * C_ + c;
    const float* lb  = lin + ((li * C_) + og * 4) * C_;

    float pvv[8];
#pragma unroll
    for (int u = 0; u < 8; ++u) pvv[u] = pwm[u * C_];
    for (int m0 = 0; m0 < C_; m0 += 8) {
        float pvn[8];
        if (m0 + 8 < C_) {
#pragma unroll
            for (int u = 0; u < 8; ++u) pvn[u] = pwm[(m0 + 8 + u) * C_];
        } else {
#pragma unroll
            for (int u = 0; u < 8; ++u) pvn[u] = 0.f;
        }
#pragma unroll
        for (int u = 0; u < 8; ++u) {
            float pv = pvv[u];
#pragma unroll
            for (int k = 0; k < 4; ++k)
                acc[k] += lb[k * C_ + (m0 + u)] * pv;
        }
#pragma unroll
        for (int u = 0; u < 8; ++u) pvv[u] = pvn[u];
    }

    float pwbc = pwb[idx * C_ + c];
    for (int k = 0; k < 4; ++k) {
        int o = og * 4 + k;
        Wcb[(idx * C_ + o) * C_ + c] = f2bf(acc[k] * aS);
        float v = acc[k] * bS + lin[(li * C_ + o) * C_ + c] * pwbc;
#pragma unroll
        for (int msk = 1; msk < 64; msk <<= 1) v += __shfl_xor(v, msk);
        if (lane == 0) red[wave] = v;
        __syncthreads();
        if (c == 0)
            Bc[idx * C_ + o] = red[0] + red[1] + red[2] + red[3] + red[4] + red[5];
        __syncthreads();
    }
}

// ---------------------------------------------------------------------------
// Kernel 5: MFMA GEMM, m97 structure: 128x128 tile, BK=32, double-buffered
// LDS staged via global_load_lds(16B), 1 barrier per K-step.
// ---------------------------------------------------------------------------
__launch_bounds__(256)
__global__ void k_gemm(const u16* __restrict__ y, const u16* __restrict__ Wcb,
                       const float* __restrict__ Bc, u16* __restrict__ qkv) {
    __shared__ __align__(16) u16 ldsA[2][4096];   // [stage][128 rows][4 chunks*8]
    __shared__ __align__(16) u16 ldsB[2][4096];

    int id = blockIdx.x;            // 0..3023
    int xcd = id & 7;
    int kb = id >> 3;               // 0..377
    int zz = kb / 21;               // 0..17
    int t  = kb % 21;
    int z  = zz * 8 + xcd;          // 0..143
    int by = t / 7, bx = t % 7;
    int idx = z >> 4, b = z & 15;

    int tid = threadIdx.x;
    int wave = tid >> 6;
    int lane = tid & 63;
    int lq = lane & 15;
    int quad = lane >> 4;
    int o_base = by * 128 + (wave & 1) * 64;          // for bias/epilogue
    int s_base_w = bx * 128 + (wave >> 1) * 64;       // for epilogue

    const u16* ybase = y + (size_t)(idx * B_ + b) * S_ * C_;
    const u16* wbase = Wcb + (size_t)idx * C_ * C_;

    // staging geometry: element e = i*256+tid covers 16B; row r=e>>2, chunk q=e&3
    int r0 = tid >> 2;              // issue-0 row (0..63); issue-1 adds 64
    int qs = (tid & 3) ^ ((r0 ^ (r0 >> 2)) & 3);   // swizzle invariant under +64
    int srA0 = bx * 128 + r0;       if (srA0 > S_ - 1) srA0 = S_ - 1;
    int srA1 = bx * 128 + r0 + 64;  if (srA1 > S_ - 1) srA1 = S_ - 1;
    const u16* gA0 = ybase + (size_t)srA0 * C_ + qs * 8;
    const u16* gA1 = ybase + (size_t)srA1 * C_ + qs * 8;
    const u16* gB0 = wbase + (size_t)(by * 128 + r0) * C_ + qs * 8;
    const u16* gB1 = wbase + (size_t)(by * 128 + r0 + 64) * C_ + qs * 8;
    int lo0 = wave * 512;           // u16 idx: wave base, issue 0
    int lo1 = 2048 + wave * 512;    // issue 1

#define STAGE(stg, kk) do {                          \
        gld16(gA0 + (kk) * 32, &ldsA[stg][lo0]);     \
        gld16(gA1 + (kk) * 32, &ldsA[stg][lo1]);     \
        gld16(gB0 + (kk) * 32, &ldsB[stg][lo0]);     \
        gld16(gB1 + (kk) * 32, &ldsB[stg][lo1]);     \
    } while (0)

    f32x4 acc[4][4];
#pragma unroll
    for (int i = 0; i < 4; ++i)
#pragma unroll
        for (int j = 0; j < 4; ++j) acc[i][j] = (f32x4){0.f,0.f,0.f,0.f};

    STAGE(0, 0);
    __syncthreads();

    int qoff = (quad ^ ((lq ^ (lq >> 2)) & 3)) * 8;   // read-side swizzle
    bf16x8 af[4], bw[4];
#pragma unroll
    for (int ks = 0; ks < 12; ++ks) {
        int cur = ks & 1;
        if (ks < 11) STAGE(cur ^ 1, ks + 1);          // async into other buffer
#pragma unroll
        for (int mt = 0; mt < 4; ++mt) {
            int sl = (wave >> 1) * 64 + mt * 16 + lq;
            __builtin_memcpy(&af[mt], &ldsA[cur][sl * 32 + qoff], 16);
        }
#pragma unroll
        for (int nt = 0; nt < 4; ++nt) {
            int ol = (wave & 1) * 64 + nt * 16 + lq;
            __builtin_memcpy(&bw[nt], &ldsB[cur][ol * 32 + qoff], 16);
        }
#pragma unroll
        for (int mt = 0; mt < 4; ++mt)
#pragma unroll
            for (int nt = 0; nt < 4; ++nt)
                acc[mt][nt] = __builtin_amdgcn_mfma_f32_16x16x32_bf16(
                    af[mt], bw[nt], acc[mt][nt], 0, 0, 0);
        __syncthreads();    // drains this step's stage (vmcnt) + frees cur buf
    }
#undef STAGE

    float bias[4];
#pragma unroll
    for (int nt = 0; nt < 4; ++nt) bias[nt] = Bc[idx * C_ + o_base + nt * 16 + lq];
    u16* obase = qkv + ((size_t)(idx * B_ + b) * S_) * C_;
#pragma unroll
    for (int mt = 0; mt < 4; ++mt) {
#pragma unroll
        for (int r = 0; r < 4; ++r) {
            int s = s_base_w + mt * 16 + quad * 4 + r;
            if (s >= S_) continue;
            u16* row = obase + (size_t)s * C_ + o_base + lq;
#pragma unroll
            for (int nt = 0; nt < 4; ++nt)
                row[nt * 16] = f2bf(acc[mt][nt][r] + bias[nt]);
        }
    }
}

// ---------------------------------------------------------------------------
// Kernel 6: MFMA flash attention, M=32/wave, no-max softmax, T=64 chunks.
// R5 structure (packed P, swizzled V b128 reads, exp2, tail split),
// __launch_bounds__(256,4). Unchanged.
// ---------------------------------------------------------------------------
__launch_bounds__(256, 4)
__global__ void k_attn(const u16* __restrict__ qkv, float* __restrict__ out) {
    __shared__ __align__(16) u16 sm[12544];   // V 8192 B @0; P 4*4224 B @8192

    int id = blockIdx.x;
    int g8 = id & 7;
    int rest = id >> 3;             // 0..251
    int qtile = rest % 7;           // 0..6
    int zh = (rest / 7) * 8 + g8;   // 0..287
    int z = zh / 6, h = zh % 6;     // z: br*16+b
    int br = z >> 4;
    int tid = threadIdx.x;
    int wave = tid >> 6;
    int lane = tid & 63;
    int lq = lane & 15;
    int quad = lane >> 4;

    int idxq = 3 * br;
    const u16* qp = qkv + (size_t)((idxq * B_ + (z & 15)) * S_) * C_ + h * HD_;
    const u16* kp = qkv + (size_t)(((idxq + 1) * B_ + (z & 15)) * S_) * C_ + h * HD_;
    const u16* vp = qkv + (size_t)(((idxq + 2) * B_ + (z & 15)) * S_) * C_ + h * HD_;

    int qbase = qtile * 128 + wave * 32;
    int qrA = qbase + lq;      if (qrA > S_ - 1) qrA = S_ - 1;
    int qrB = qbase + 16 + lq; if (qrB > S_ - 1) qrB = S_ - 1;
    const u16* qpa = qp + (size_t)qrA * C_ + quad * 8;
    const u16* qpb = qp + (size_t)qrB * C_ + quad * 8;
    bf16x8 aqA0 = *(const bf16x8*)qpa;
    bf16x8 aqA1 = *(const bf16x8*)(qpa + 32);
    bf16x8 aqB0 = *(const bf16x8*)qpb;
    bf16x8 aqB1 = *(const bf16x8*)(qpb + 32);

    f32x4 oA[4], oB[4];
#pragma unroll
    for (int i = 0; i < 4; ++i) { oA[i] = (f32x4){0.f,0.f,0.f,0.f}; oB[i] = oA[i]; }
    float rsA[4] = {0.f,0.f,0.f,0.f}, rsB[4] = {0.f,0.f,0.f,0.f};

    // V staging: 2 consecutive t, 8 d per thread (256 thr cover 64t x 64d)
    int t2 = (tid & 31) * 2;        // 0..62
    int dg = (tid >> 5) * 8;        // 0..56
    char* smb = (char*)sm;
    // V write addresses: byte = d*128 + ((t2/8 ^ (d&7))<<4) + (t2&7)*2, d=dg+e
    // P buffer (u32 view): per-wave base, rows=q (0..15), stride 66 u32
    u32* pb0 = (u32*)sm + 2048 + wave * 1056;
    u32* pwr = pb0 + (quad * 4) * 66 + lq;       // store base: + r*66 + tt*16
    const u32* prd = pb0 + lq * 66 + quad * 8;   // read base: + n*32 + j
    int sw = lq & 7;                              // V read swizzle key
    int vrb0 = lq * 128 + ((quad ^ sw) << 4);          // kh=0 V-frag byte base
    int vrb1 = lq * 128 + (((4 + quad) ^ sw) << 4);    // kh=1

#define VSTAGE(TG0, TG1) do {                                              \
        bf16x8 v0 = *(const bf16x8*)(vp + (size_t)(TG0) * C_ + dg);        \
        bf16x8 v1 = *(const bf16x8*)(vp + (size_t)(TG1) * C_ + dg);        \
        __syncthreads();                                                   \
        _Pragma("unroll")                                                  \
        for (int e = 0; e < 8; ++e) {                                      \
            u32 pk = (u32)(u16)v0[e] | ((u32)(u16)v1[e] << 16);            \
            *(u32*)(smb + (dg + e) * 128 + ((((t2 >> 3) ^ e)) << 4)        \
                    + ((t2 & 7) << 1)) = pk;                               \
        }                                                                  \
        __syncthreads();                                                   \
    } while (0)

    for (int ch = 0; ch < 12; ++ch) {
        int tc = ch * 64;
        VSTAGE(tc + t2, tc + t2 + 1);

        // ---- QK^T + exp + packed P-store, per 16-t tile (all t live)
#pragma unroll
        for (int tt = 0; tt < 4; ++tt) {
            const u16* kptr = kp + (size_t)(tc + tt * 16 + lq) * C_ + quad * 8;
            bf16x8 bk0 = *(const bf16x8*)kptr;
            bf16x8 bk1 = *(const bf16x8*)(kptr + 32);
            f32x4 sA = {0.f,0.f,0.f,0.f}, sB = sA;
            sA = __builtin_amdgcn_mfma_f32_16x16x32_bf16(aqA0, bk0, sA, 0, 0, 0);
            sA = __builtin_amdgcn_mfma_f32_16x16x32_bf16(aqA1, bk1, sA, 0, 0, 0);
            sB = __builtin_amdgcn_mfma_f32_16x16x32_bf16(aqB0, bk0, sB, 0, 0, 0);
            sB = __builtin_amdgcn_mfma_f32_16x16x32_bf16(aqB1, bk1, sB, 0, 0, 0);
#pragma unroll
            for (int r = 0; r < 4; ++r) {
                float ea = exp2_fast(sA[r] * LSC_);
                float eb = exp2_fast(sB[r] * LSC_);
                u32 ua = __float_as_uint(ea) & 0xFFFF0000u;   // trunc bf16
                u32 ub = __float_as_uint(eb) & 0xFFFF0000u;
                rsA[r] += __uint_as_float(ua);    // consistent w/ numerator
                rsB[r] += __uint_as_float(ub);
                // pk = {eb.hi16, ea.hi16}
                pwr[r * 66 + tt * 16] = __builtin_amdgcn_perm(
                    __float_as_uint(eb), __float_as_uint(ea), 0x07060302u);
            }
        }

        // ---- P A-frags (shared reads, perm unpack; memcpy orders vs stores)
        bf16x8 apA[2], apB[2];
#pragma unroll
        for (int n = 0; n < 2; ++n) {
            u32 uu[8];
            __builtin_memcpy(uu, prd + n * 32, 32);
            union { u32 w[4]; bf16x8 v; } ca, cb;
#pragma unroll
            for (int jj = 0; jj < 4; ++jj) {
                ca.w[jj] = __builtin_amdgcn_perm(uu[2*jj+1], uu[2*jj], 0x05040100u);
                cb.w[jj] = __builtin_amdgcn_perm(uu[2*jj+1], uu[2*jj], 0x07060302u);
            }
            apA[n] = ca.v; apB[n] = cb.v;
        }

        // ---- PV: swizzled aligned b128 V-frags, shared by both rowsets
#pragma unroll
        for (int dt = 0; dt < 4; ++dt) {
            bf16x8 bv0, bv1;
            __builtin_memcpy(&bv0, smb + dt * 2048 + vrb0, 16);
            __builtin_memcpy(&bv1, smb + dt * 2048 + vrb1, 16);
            oA[dt] = __builtin_amdgcn_mfma_f32_16x16x32_bf16(apA[0], bv0, oA[dt], 0, 0, 0);
            oB[dt] = __builtin_amdgcn_mfma_f32_16x16x32_bf16(apB[0], bv0, oB[dt], 0, 0, 0);
            oA[dt] = __builtin_amdgcn_mfma_f32_16x16x32_bf16(apA[1], bv1, oA[dt], 0, 0, 0);
            oB[dt] = __builtin_amdgcn_mfma_f32_16x16x32_bf16(apB[1], bv1, oB[dt], 0, 0, 0);
        }
    }

    // ---- tail chunk: t 768..783 live (16 of 64)
    {
        int tc = 768;
        int tg0 = tc + t2;     if (tg0 > S_ - 1) tg0 = S_ - 1;
        int tg1 = tc + t2 + 1; if (tg1 > S_ - 1) tg1 = S_ - 1;
        VSTAGE(tg0, tg1);

        const u16* kptr = kp + (size_t)(tc + lq) * C_ + quad * 8;
        bf16x8 bk0 = *(const bf16x8*)kptr;
        bf16x8 bk1 = *(const bf16x8*)(kptr + 32);
        f32x4 sA = {0.f,0.f,0.f,0.f}, sB = sA;
        sA = __builtin_amdgcn_mfma_f32_16x16x32_bf16(aqA0, bk0, sA, 0, 0, 0);
        sA = __builtin_amdgcn_mfma_f32_16x16x32_bf16(aqA1, bk1, sA, 0, 0, 0);
        sB = __builtin_amdgcn_mfma_f32_16x16x32_bf16(aqB0, bk0, sB, 0, 0, 0);
        sB = __builtin_amdgcn_mfma_f32_16x16x32_bf16(aqB1, bk1, sB, 0, 0, 0);
#pragma unroll
        for (int r = 0; r < 4; ++r) {
            float ea = exp2_fast(sA[r] * LSC_);
            float eb = exp2_fast(sB[r] * LSC_);
            u32 ua = __float_as_uint(ea) & 0xFFFF0000u;
            u32 ub = __float_as_uint(eb) & 0xFFFF0000u;
            rsA[r] += __uint_as_float(ua);
            rsB[r] += __uint_as_float(ub);
            pwr[r * 66]      = __builtin_amdgcn_perm(
                __float_as_uint(eb), __float_as_uint(ea), 0x07060302u);
            pwr[r * 66 + 16] = 0;               // zero t 16..31 (dead)
        }

        bf16x8 apA0, apB0;
        {
            u32 uu[8];
            __builtin_memcpy(uu, prd, 32);
            union { u32 w[4]; bf16x8 v; } ca, cb;
#pragma unroll
            for (int jj = 0; jj < 4; ++jj) {
                ca.w[jj] = __builtin_amdgcn_perm(uu[2*jj+1], uu[2*jj], 0x05040100u);
                cb.w[jj] = __builtin_amdgcn_perm(uu[2*jj+1], uu[2*jj], 0x07060302u);
            }
            apA0 = ca.v; apB0 = cb.v;
        }
#pragma unroll
        for (int dt = 0; dt < 4; ++dt) {
            bf16x8 bv0;
            __builtin_memcpy(&bv0, smb + dt * 2048 + vrb0, 16);
            oA[dt] = __builtin_amdgcn_mfma_f32_16x16x32_bf16(apA0, bv0, oA[dt], 0, 0, 0);
            oB[dt] = __builtin_amdgcn_mfma_f32_16x16x32_bf16(apB0, bv0, oB[dt], 0, 0, 0);
        }
    }
#undef VSTAGE

    // ---- final l reduction (once, 16-lane row groups)
#pragma unroll
    for (int msk = 1; msk <= 8; msk <<= 1)
#pragma unroll
        for (int r = 0; r < 4; ++r) {
            rsA[r] += __shfl_xor(rsA[r], msk);
            rsB[r] += __shfl_xor(rsB[r], msk);
        }

    // ---- epilogue
    size_t obase = ((size_t)z * NH_ + h) * S_ * HD_;
#pragma unroll
    for (int r = 0; r < 4; ++r) {
        int qa = qbase + quad * 4 + r;
        if (qa < S_) {
            float inv = 1.f / rsA[r];
            float* dst = out + obase + (size_t)qa * HD_ + lq;
            dst[0]  = oA[0][r] * inv;
            dst[16] = oA[1][r] * inv;
            dst[32] = oA[2][r] * inv;
            dst[48] = oA[3][r] * inv;
        }
        int qb = qbase + 16 + quad * 4 + r;
        if (qb < S_) {
            float inv = 1.f / rsB[r];
            float* dst = out + obase + (size_t)qb * HD_ + lq;
            dst[0]  = oB[0][r] * inv;
            dst[16] = oB[1][r] * inv;
            dst[32] = oB[2][r] * inv;
            dst[48] = oB[3][r] * inv;
        }
    }
}

// ---------------------------------------------------------------------------
extern "C" void kernel_launch(void* const* d_in, const int* in_sizes, int n_in,
                              void* d_out, int out_size, void* d_ws, size_t ws_size,
                              hipStream_t stream) {
    (void)in_sizes; (void)n_in; (void)out_size; (void)ws_size;
    const float* x1    = (const float*)d_in[0];
    const float* x2    = (const float*)d_in[3];
    const float* dw    = (const float*)d_in[6];
    const float* gamma = (const float*)d_in[7];
    const float* beta  = (const float*)d_in[8];
    const float* pw    = (const float*)d_in[9];
    const float* pwb   = (const float*)d_in[10];
    const float* lin   = (const float*)d_in[11];
    float* out = (float*)d_out;

    char* ws = (char*)d_ws;
    // ws layout (bytes):
    // y    bf16 [9][16][784][384]  @ 28901376   size 86,704,128
    // qkv  bf16 [9][16][784][384]  @ 115605504  size 86,704,128
    // Wcb  bf16 [9][384][384]      @ 202309632  size 2,654,208
    // Bc   f32  [9][384]           @ 204963840  size 13,824
    // part f32  [9][384][2]        @ 205005312  size 27,648 (memset to 0)
    u16*  y   = (u16*)(ws + 28901376);
    u16*  qkv = (u16*)(ws + 115605504);
    u16*  Wcb = (u16*)(ws + 202309632);
    float* Bc = (float*)(ws + 204963840);
    float* part = (float*)(ws + 205005312);

    hipMemsetAsync(part, 0, 9 * C_ * 2 * sizeof(float), stream);
    k_conv  <<<dim3(4032), 128, 0, stream>>>(x1, x2, dw, y, part);
    k_wcomb <<<dim3(864), 384, 0, stream>>>(pw, pwb, lin, part, gamma, beta, Wcb, Bc);
    k_gemm  <<<dim3(3024), 256, 0, stream>>>(y, Wcb, Bc, qkv);
    k_attn  <<<dim3(2016), 256, 0, stream>>>(qkv, out);
}

// Round 9
// 424.470 us; speedup vs baseline: 1.0736x; 1.0063x over previous
//
#include <hip/hip_runtime.h>

typedef unsigned short u16;
typedef unsigned int u32;
typedef unsigned long long u64;

#define B_   16
#define C_   384
#define H_   28
#define W_   28
#define S_   784
#define NH_  6
#define HD_  64
#define BS_  (B_ * S_)            // 12544
#define SCALE_ 0.05103103630798288f  // 384^-0.5
#define LSC_   0.07362225484151387f  // SCALE_ * log2(e): exp(s*SCALE) = 2^(s*LSC)
#define EPS_ 1e-5f

typedef __attribute__((ext_vector_type(8))) short bf16x8;
typedef __attribute__((ext_vector_type(4))) float f32x4;

__device__ __forceinline__ float bf2f(u16 u) {
    return __uint_as_float(((u32)u) << 16);
}
__device__ __forceinline__ u16 f2bf(float f) {
    u32 x = __float_as_uint(f);
    u32 r = (x + 0x7fffu + ((x >> 16) & 1u)) >> 16;   // RNE
    return (u16)r;
}

// async global->LDS 16B per lane; dest = wave-uniform base + lane*16 (HW rule)
__device__ __forceinline__ void gld16(const u16* g, u16* l) {
    __builtin_amdgcn_global_load_lds(
        (__attribute__((address_space(1))) void*)g,
        (__attribute__((address_space(3))) void*)l, 16, 0, 0);
}

__device__ __forceinline__ float exp2_fast(float x) {
    float r;
    asm("v_exp_f32 %0, %1" : "=v"(r) : "v"(x));
    return r;
}

// ---------------------------------------------------------------------------
// Kernel 2 (fused, 3-in-1 by input group): depthwise 3x3 conv.
// R9: BRANCH-FREE body. Every previous version kept a wave-uniform g-branch
// diamond around each column load (3 loads in 3 basic blocks, each with its
// own waitcnt -> un-batchable, serialized latency per iteration; why R6 ILP,
// R7 TLP, R8 load-reorder were all ~neutral). Now: always load BOTH streams,
// blend with constant 0/1 weights, kill out-of-range taps with 0/1 float
// masks on clamped addresses. 6 loads issue in one burst, one waitcnt, zero
// control flow. Blend math is exact (*1, *0, +0) -> results unchanged.
// Extra cross-stream reads are L2 hits (XCD swizzle co-locates all g of b).
// ---------------------------------------------------------------------------
__launch_bounds__(128)
__global__ void k_conv(const float* __restrict__ x1, const float* __restrict__ x2,
                       const float* __restrict__ dw, u16* __restrict__ y,
                       float* __restrict__ part) {
    int id = blockIdx.x;            // 0..4031
    int xcd = id & 7;
    int r = id >> 3;                // 0..503
    int cc = r % 3;
    int rr = r / 3;                 // 0..167
    int p = xcd + 8 * (rr / 28);    // 0..47
    int h = rr % 28;                // 0..27
    int g = p / 16;                 // input group (wave-uniform)
    int b = p % 16;
    int c = cc * 128 + threadIdx.x; // 0..383

    const float* pa = x1 + (size_t)b * S_ * C_ + c;
    const float* pb = x2 + (size_t)b * S_ * C_ + c;
    float s0 = (g == 1) ? 0.f : 1.f;    // x1 blend weight
    float s1 = (g == 0) ? 0.f : 1.f;    // x2 blend weight

    float wt[3][9];
#pragma unroll
    for (int i = 0; i < 3; ++i)
#pragma unroll
        for (int t = 0; t < 9; ++t)
            wt[i][t] = dw[((3 * g + i) * C_ + c) * 9 + t];

    // per-row 0/1 masks + clamped row offsets (mask kills clamped values)
    float rm[3];
    size_t ro[3];
#pragma unroll
    for (int dh = 0; dh < 3; ++dh) {
        int hh = h + dh - 1;
        rm[dh] = (hh >= 0 && hh < H_) ? 1.f : 0.f;
        int hc = hh < 0 ? 0 : (hh > H_ - 1 ? H_ - 1 : hh);
        ro[dh] = (size_t)(hc * W_) * C_;
    }

    // sliding window: a[dh][0..2] = cols w-1, w, w+1 (blended, masked)
    float a[3][3];
#pragma unroll
    for (int dh = 0; dh < 3; ++dh) {
        a[dh][0] = 0.f;
        a[dh][1] = (pa[ro[dh]] * s0 + pb[ro[dh]] * s1) * rm[dh];
        a[dh][2] = (pa[ro[dh] + C_] * s0 + pb[ro[dh] + C_] * s1) * rm[dh];
    }

    u16* dst[3];
#pragma unroll
    for (int i = 0; i < 3; ++i)
        dst[i] = y + ((size_t)((3 * g + i) * B_ + b) * S_ + h * W_) * C_ + c;

    float sum[3] = {0.f, 0.f, 0.f}, sq[3] = {0.f, 0.f, 0.f};

#pragma unroll 4
    for (int w = 0; w < W_; ++w) {
        // ---- next column: 6 loads in one burst (branch-free, clamped+masked)
        int wn = w + 2;
        float wm = (wn < W_) ? 1.f : 0.f;
        int wc = (wn < W_) ? wn : (W_ - 1);
        size_t o0 = ro[0] + (size_t)wc * C_;
        size_t o1 = ro[1] + (size_t)wc * C_;
        size_t o2 = ro[2] + (size_t)wc * C_;
        float la0 = pa[o0], lb0 = pb[o0];
        float la1 = pa[o1], lb1 = pb[o1];
        float la2 = pa[o2], lb2 = pb[o2];
        float nx0 = (la0 * s0 + lb0 * s1) * (rm[0] * wm);
        float nx1 = (la1 * s0 + lb1 * s1) * (rm[1] * wm);
        float nx2 = (la2 * s0 + lb2 * s1) * (rm[2] * wm);

        // ---- compute + stores
#pragma unroll
        for (int i = 0; i < 3; ++i) {
            const float* W9 = wt[i];
            float acc = a[0][0]*W9[0] + a[0][1]*W9[1] + a[0][2]*W9[2]
                      + a[1][0]*W9[3] + a[1][1]*W9[4] + a[1][2]*W9[5]
                      + a[2][0]*W9[6] + a[2][1]*W9[7] + a[2][2]*W9[8];
            sum[i] += acc;
            sq[i] = fmaf(acc, acc, sq[i]);
            dst[i][w * C_] = f2bf(acc);
        }
        // ---- slide (renamed away by unroll)
        a[0][0] = a[0][1]; a[0][1] = a[0][2]; a[0][2] = nx0;
        a[1][0] = a[1][1]; a[1][1] = a[1][2]; a[1][2] = nx1;
        a[2][0] = a[2][1]; a[2][1] = a[2][2]; a[2][2] = nx2;
    }
#pragma unroll
    for (int i = 0; i < 3; ++i) {
        atomicAdd(&part[((3 * g + i) * C_ + c) * 2],     sum[i]);
        atomicAdd(&part[((3 * g + i) * C_ + c) * 2 + 1], sq[i]);
    }
}

// ---------------------------------------------------------------------------
// Kernel 4: combined weights. Wcb (bf16) [idx][o][c] = lin@pw * aScale[c];
// Bc[idx][o] = (lin@pw)@bShift + lin@pwb.
// R8 structure: grid 864 (og split 96/idx), XCD-aware idx mapping, 8x
// m-unroll with batched pv prefetch, BN finalize inlined.
// ---------------------------------------------------------------------------
__global__ void k_wcomb(const float* __restrict__ pw, const float* __restrict__ pwb,
                        const float* __restrict__ lin,
                        const float* __restrict__ part,
                        const float* __restrict__ gamma, const float* __restrict__ beta,
                        u16* __restrict__ Wcb, float* __restrict__ Bc) {
    __shared__ float red[8];
    int id = blockIdx.x;            // 0..863
    int xcd = id & 7;
    int k2 = id >> 3;               // 0..107
    int idx, og;
    if (k2 < 96) { idx = xcd; og = k2; }
    else         { idx = 8;   og = xcd * 12 + (k2 - 96); }
    int c = threadIdx.x;            // 0..383
    int wave = c >> 6, lane = c & 63;
    int li = (idx < 3) ? idx : 3 + (idx % 3);   // replicate branch-2 lin reuse bug

    // inline BN finalize (same op order as old k_stats2)
    float s_ = part[(idx * C_ + c) * 2];
    float q_ = part[(idx * C_ + c) * 2 + 1];
    float mean = s_ / (float)BS_;
    float var  = q_ / (float)BS_ - mean * mean;
    float aS = gamma[idx * C_ + c] * rsqrtf(var + EPS_);
    float bS = beta[idx * C_ + c] - mean * aS;

    float acc[4];
#pragma unroll
    for (int k = 0; k < 4; ++k) acc[k] = 0.f;
    const float* pwm = pw + (idx * C_) * C_ + c;
    const float* lb  = lin + ((li * C_) + og * 4) * C_;

    float pvv[8];
#pragma unroll
    for (int u = 0; u < 8; ++u) pvv[u] = pwm[u * C_];
    for (int m0 = 0; m0 < C_; m0 += 8) {
        float pvn[8];
        if (m0 + 8 < C_) {
#pragma unroll
            for (int u = 0; u < 8; ++u) pvn[u] = pwm[(m0 + 8 + u) * C_];
        } else {
#pragma unroll
            for (int u = 0; u < 8; ++u) pvn[u] = 0.f;
        }
#pragma unroll
        for (int u = 0; u < 8; ++u) {
            float pv = pvv[u];
#pragma unroll
            for (int k = 0; k < 4; ++k)
                acc[k] += lb[k * C_ + (m0 + u)] * pv;
        }
#pragma unroll
        for (int u = 0; u < 8; ++u) pvv[u] = pvn[u];
    }

    float pwbc = pwb[idx * C_ + c];
    for (int k = 0; k < 4; ++k) {
        int o = og * 4 + k;
        Wcb[(idx * C_ + o) * C_ + c] = f2bf(acc[k] * aS);
        float v = acc[k] * bS + lin[(li * C_ + o) * C_ + c] * pwbc;
#pragma unroll
        for (int msk = 1; msk < 64; msk <<= 1) v += __shfl_xor(v, msk);
        if (lane == 0) red[wave] = v;
        __syncthreads();
        if (c == 0)
            Bc[idx * C_ + o] = red[0] + red[1] + red[2] + red[3] + red[4] + red[5];
        __syncthreads();
    }
}

// ---------------------------------------------------------------------------
// Kernel 5: MFMA GEMM, m97 structure: 128x128 tile, BK=32, double-buffered
// LDS staged via global_load_lds(16B), 1 barrier per K-step.
// ---------------------------------------------------------------------------
__launch_bounds__(256)
__global__ void k_gemm(const u16* __restrict__ y, const u16* __restrict__ Wcb,
                       const float* __restrict__ Bc, u16* __restrict__ qkv) {
    __shared__ __align__(16) u16 ldsA[2][4096];   // [stage][128 rows][4 chunks*8]
    __shared__ __align__(16) u16 ldsB[2][4096];

    int id = blockIdx.x;            // 0..3023
    int xcd = id & 7;
    int kb = id >> 3;               // 0..377
    int zz = kb / 21;               // 0..17
    int t  = kb % 21;
    int z  = zz * 8 + xcd;          // 0..143
    int by = t / 7, bx = t % 7;
    int idx = z >> 4, b = z & 15;

    int tid = threadIdx.x;
    int wave = tid >> 6;
    int lane = tid & 63;
    int lq = lane & 15;
    int quad = lane >> 4;
    int o_base = by * 128 + (wave & 1) * 64;          // for bias/epilogue
    int s_base_w = bx * 128 + (wave >> 1) * 64;       // for epilogue

    const u16* ybase = y + (size_t)(idx * B_ + b) * S_ * C_;
    const u16* wbase = Wcb + (size_t)idx * C_ * C_;

    // staging geometry: element e = i*256+tid covers 16B; row r=e>>2, chunk q=e&3
    int r0 = tid >> 2;              // issue-0 row (0..63); issue-1 adds 64
    int qs = (tid & 3) ^ ((r0 ^ (r0 >> 2)) & 3);   // swizzle invariant under +64
    int srA0 = bx * 128 + r0;       if (srA0 > S_ - 1) srA0 = S_ - 1;
    int srA1 = bx * 128 + r0 + 64;  if (srA1 > S_ - 1) srA1 = S_ - 1;
    const u16* gA0 = ybase + (size_t)srA0 * C_ + qs * 8;
    const u16* gA1 = ybase + (size_t)srA1 * C_ + qs * 8;
    const u16* gB0 = wbase + (size_t)(by * 128 + r0) * C_ + qs * 8;
    const u16* gB1 = wbase + (size_t)(by * 128 + r0 + 64) * C_ + qs * 8;
    int lo0 = wave * 512;           // u16 idx: wave base, issue 0
    int lo1 = 2048 + wave * 512;    // issue 1

#define STAGE(stg, kk) do {                          \
        gld16(gA0 + (kk) * 32, &ldsA[stg][lo0]);     \
        gld16(gA1 + (kk) * 32, &ldsA[stg][lo1]);     \
        gld16(gB0 + (kk) * 32, &ldsB[stg][lo0]);     \
        gld16(gB1 + (kk) * 32, &ldsB[stg][lo1]);     \
    } while (0)

    f32x4 acc[4][4];
#pragma unroll
    for (int i = 0; i < 4; ++i)
#pragma unroll
        for (int j = 0; j < 4; ++j) acc[i][j] = (f32x4){0.f,0.f,0.f,0.f};

    STAGE(0, 0);
    __syncthreads();

    int qoff = (quad ^ ((lq ^ (lq >> 2)) & 3)) * 8;   // read-side swizzle
    bf16x8 af[4], bw[4];
#pragma unroll
    for (int ks = 0; ks < 12; ++ks) {
        int cur = ks & 1;
        if (ks < 11) STAGE(cur ^ 1, ks + 1);          // async into other buffer
#pragma unroll
        for (int mt = 0; mt < 4; ++mt) {
            int sl = (wave >> 1) * 64 + mt * 16 + lq;
            __builtin_memcpy(&af[mt], &ldsA[cur][sl * 32 + qoff], 16);
        }
#pragma unroll
        for (int nt = 0; nt < 4; ++nt) {
            int ol = (wave & 1) * 64 + nt * 16 + lq;
            __builtin_memcpy(&bw[nt], &ldsB[cur][ol * 32 + qoff], 16);
        }
#pragma unroll
        for (int mt = 0; mt < 4; ++mt)
#pragma unroll
            for (int nt = 0; nt < 4; ++nt)
                acc[mt][nt] = __builtin_amdgcn_mfma_f32_16x16x32_bf16(
                    af[mt], bw[nt], acc[mt][nt], 0, 0, 0);
        __syncthreads();    // drains this step's stage (vmcnt) + frees cur buf
    }
#undef STAGE

    float bias[4];
#pragma unroll
    for (int nt = 0; nt < 4; ++nt) bias[nt] = Bc[idx * C_ + o_base + nt * 16 + lq];
    u16* obase = qkv + ((size_t)(idx * B_ + b) * S_) * C_;
#pragma unroll
    for (int mt = 0; mt < 4; ++mt) {
#pragma unroll
        for (int r = 0; r < 4; ++r) {
            int s = s_base_w + mt * 16 + quad * 4 + r;
            if (s >= S_) continue;
            u16* row = obase + (size_t)s * C_ + o_base + lq;
#pragma unroll
            for (int nt = 0; nt < 4; ++nt)
                row[nt * 16] = f2bf(acc[mt][nt][r] + bias[nt]);
        }
    }
}

// ---------------------------------------------------------------------------
// Kernel 6: MFMA flash attention, M=32/wave, no-max softmax, T=64 chunks.
// R5 structure (packed P, swizzled V b128 reads, exp2, tail split),
// __launch_bounds__(256,4). Unchanged.
// ---------------------------------------------------------------------------
__launch_bounds__(256, 4)
__global__ void k_attn(const u16* __restrict__ qkv, float* __restrict__ out) {
    __shared__ __align__(16) u16 sm[12544];   // V 8192 B @0; P 4*4224 B @8192

    int id = blockIdx.x;
    int g8 = id & 7;
    int rest = id >> 3;             // 0..251
    int qtile = rest % 7;           // 0..6
    int zh = (rest / 7) * 8 + g8;   // 0..287
    int z = zh / 6, h = zh % 6;     // z: br*16+b
    int br = z >> 4;
    int tid = threadIdx.x;
    int wave = tid >> 6;
    int lane = tid & 63;
    int lq = lane & 15;
    int quad = lane >> 4;

    int idxq = 3 * br;
    const u16* qp = qkv + (size_t)((idxq * B_ + (z & 15)) * S_) * C_ + h * HD_;
    const u16* kp = qkv + (size_t)(((idxq + 1) * B_ + (z & 15)) * S_) * C_ + h * HD_;
    const u16* vp = qkv + (size_t)(((idxq + 2) * B_ + (z & 15)) * S_) * C_ + h * HD_;

    int qbase = qtile * 128 + wave * 32;
    int qrA = qbase + lq;      if (qrA > S_ - 1) qrA = S_ - 1;
    int qrB = qbase + 16 + lq; if (qrB > S_ - 1) qrB = S_ - 1;
    const u16* qpa = qp + (size_t)qrA * C_ + quad * 8;
    const u16* qpb = qp + (size_t)qrB * C_ + quad * 8;
    bf16x8 aqA0 = *(const bf16x8*)qpa;
    bf16x8 aqA1 = *(const bf16x8*)(qpa + 32);
    bf16x8 aqB0 = *(const bf16x8*)qpb;
    bf16x8 aqB1 = *(const bf16x8*)(qpb + 32);

    f32x4 oA[4], oB[4];
#pragma unroll
    for (int i = 0; i < 4; ++i) { oA[i] = (f32x4){0.f,0.f,0.f,0.f}; oB[i] = oA[i]; }
    float rsA[4] = {0.f,0.f,0.f,0.f}, rsB[4] = {0.f,0.f,0.f,0.f};

    // V staging: 2 consecutive t, 8 d per thread (256 thr cover 64t x 64d)
    int t2 = (tid & 31) * 2;        // 0..62
    int dg = (tid >> 5) * 8;        // 0..56
    char* smb = (char*)sm;
    // V write addresses: byte = d*128 + ((t2/8 ^ (d&7))<<4) + (t2&7)*2, d=dg+e
    // P buffer (u32 view): per-wave base, rows=q (0..15), stride 66 u32
    u32* pb0 = (u32*)sm + 2048 + wave * 1056;
    u32* pwr = pb0 + (quad * 4) * 66 + lq;       // store base: + r*66 + tt*16
    const u32* prd = pb0 + lq * 66 + quad * 8;   // read base: + n*32 + j
    int sw = lq & 7;                              // V read swizzle key
    int vrb0 = lq * 128 + ((quad ^ sw) << 4);          // kh=0 V-frag byte base
    int vrb1 = lq * 128 + (((4 + quad) ^ sw) << 4);    // kh=1

#define VSTAGE(TG0, TG1) do {                                              \
        bf16x8 v0 = *(const bf16x8*)(vp + (size_t)(TG0) * C_ + dg);        \
        bf16x8 v1 = *(const bf16x8*)(vp + (size_t)(TG1) * C_ + dg);        \
        __syncthreads();                                                   \
        _Pragma("unroll")                                                  \
        for (int e = 0; e < 8; ++e) {                                      \
            u32 pk = (u32)(u16)v0[e] | ((u32)(u16)v1[e] << 16);            \
            *(u32*)(smb + (dg + e) * 128 + ((((t2 >> 3) ^ e)) << 4)        \
                    + ((t2 & 7) << 1)) = pk;                               \
        }                                                                  \
        __syncthreads();                                                   \
    } while (0)

    for (int ch = 0; ch < 12; ++ch) {
        int tc = ch * 64;
        VSTAGE(tc + t2, tc + t2 + 1);

        // ---- QK^T + exp + packed P-store, per 16-t tile (all t live)
#pragma unroll
        for (int tt = 0; tt < 4; ++tt) {
            const u16* kptr = kp + (size_t)(tc + tt * 16 + lq) * C_ + quad * 8;
            bf16x8 bk0 = *(const bf16x8*)kptr;
            bf16x8 bk1 = *(const bf16x8*)(kptr + 32);
            f32x4 sA = {0.f,0.f,0.f,0.f}, sB = sA;
            sA = __builtin_amdgcn_mfma_f32_16x16x32_bf16(aqA0, bk0, sA, 0, 0, 0);
            sA = __builtin_amdgcn_mfma_f32_16x16x32_bf16(aqA1, bk1, sA, 0, 0, 0);
            sB = __builtin_amdgcn_mfma_f32_16x16x32_bf16(aqB0, bk0, sB, 0, 0, 0);
            sB = __builtin_amdgcn_mfma_f32_16x16x32_bf16(aqB1, bk1, sB, 0, 0, 0);
#pragma unroll
            for (int r = 0; r < 4; ++r) {
                float ea = exp2_fast(sA[r] * LSC_);
                float eb = exp2_fast(sB[r] * LSC_);
                u32 ua = __float_as_uint(ea) & 0xFFFF0000u;   // trunc bf16
                u32 ub = __float_as_uint(eb) & 0xFFFF0000u;
                rsA[r] += __uint_as_float(ua);    // consistent w/ numerator
                rsB[r] += __uint_as_float(ub);
                // pk = {eb.hi16, ea.hi16}
                pwr[r * 66 + tt * 16] = __builtin_amdgcn_perm(
                    __float_as_uint(eb), __float_as_uint(ea), 0x07060302u);
            }
        }

        // ---- P A-frags (shared reads, perm unpack; memcpy orders vs stores)
        bf16x8 apA[2], apB[2];
#pragma unroll
        for (int n = 0; n < 2; ++n) {
            u32 uu[8];
            __builtin_memcpy(uu, prd + n * 32, 32);
            union { u32 w[4]; bf16x8 v; } ca, cb;
#pragma unroll
            for (int jj = 0; jj < 4; ++jj) {
                ca.w[jj] = __builtin_amdgcn_perm(uu[2*jj+1], uu[2*jj], 0x05040100u);
                cb.w[jj] = __builtin_amdgcn_perm(uu[2*jj+1], uu[2*jj], 0x07060302u);
            }
            apA[n] = ca.v; apB[n] = cb.v;
        }

        // ---- PV: swizzled aligned b128 V-frags, shared by both rowsets
#pragma unroll
        for (int dt = 0; dt < 4; ++dt) {
            bf16x8 bv0, bv1;
            __builtin_memcpy(&bv0, smb + dt * 2048 + vrb0, 16);
            __builtin_memcpy(&bv1, smb + dt * 2048 + vrb1, 16);
            oA[dt] = __builtin_amdgcn_mfma_f32_16x16x32_bf16(apA[0], bv0, oA[dt], 0, 0, 0);
            oB[dt] = __builtin_amdgcn_mfma_f32_16x16x32_bf16(apB[0], bv0, oB[dt], 0, 0, 0);
            oA[dt] = __builtin_amdgcn_mfma_f32_16x16x32_bf16(apA[1], bv1, oA[dt], 0, 0, 0);
            oB[dt] = __builtin_amdgcn_mfma_f32_16x16x32_bf16(apB[1], bv1, oB[dt], 0, 0, 0);
        }
    }

    // ---- tail chunk: t 768..783 live (16 of 64)
    {
        int tc = 768;
        int tg0 = tc + t2;     if (tg0 > S_ - 1) tg0 = S_ - 1;
        int tg1 = tc + t2 + 1; if (tg1 > S_ - 1) tg1 = S_ - 1;
        VSTAGE(tg0, tg1);

        const u16* kptr = kp + (size_t)(tc + lq) * C_ + quad * 8;
        bf16x8 bk0 = *(const bf16x8*)kptr;
        bf16x8 bk1 = *(const bf16x8*)(kptr + 32);
        f32x4 sA = {0.f,0.f,0.f,0.f}, sB = sA;
        sA = __builtin_amdgcn_mfma_f32_16x16x32_bf16(aqA0, bk0, sA, 0, 0, 0);
        sA = __builtin_amdgcn_mfma_f32_16x16x32_bf16(aqA1, bk1, sA, 0, 0, 0);
        sB = __builtin_amdgcn_mfma_f32_16x16x32_bf16(aqB0, bk0, sB, 0, 0, 0);
        sB = __builtin_amdgcn_mfma_f32_16x16x32_bf16(aqB1, bk1, sB, 0, 0, 0);
#pragma unroll
        for (int r = 0; r < 4; ++r) {
            float ea = exp2_fast(sA[r] * LSC_);
            float eb = exp2_fast(sB[r] * LSC_);
            u32 ua = __float_as_uint(ea) & 0xFFFF0000u;
            u32 ub = __float_as_uint(eb) & 0xFFFF0000u;
            rsA[r] += __uint_as_float(ua);
            rsB[r] += __uint_as_float(ub);
            pwr[r * 66]      = __builtin_amdgcn_perm(
                __float_as_uint(eb), __float_as_uint(ea), 0x07060302u);
            pwr[r * 66 + 16] = 0;               // zero t 16..31 (dead)
        }

        bf16x8 apA0, apB0;
        {
            u32 uu[8];
            __builtin_memcpy(uu, prd, 32);
            union { u32 w[4]; bf16x8 v; } ca, cb;
#pragma unroll
            for (int jj = 0; jj < 4; ++jj) {
                ca.w[jj] = __builtin_amdgcn_perm(uu[2*jj+1], uu[2*jj], 0x05040100u);
                cb.w[jj] = __builtin_amdgcn_perm(uu[2*jj+1], uu[2*jj], 0x07060302u);
            }
            apA0 = ca.v; apB0 = cb.v;
        }
#pragma unroll
        for (int dt = 0; dt < 4; ++dt) {
            bf16x8 bv0;
            __builtin_memcpy(&bv0, smb + dt * 2048 + vrb0, 16);
            oA[dt] = __builtin_amdgcn_mfma_f32_16x16x32_bf16(apA0, bv0, oA[dt], 0, 0, 0);
            oB[dt] = __builtin_amdgcn_mfma_f32_16x16x32_bf16(apB0, bv0, oB[dt], 0, 0, 0);
        }
    }
#undef VSTAGE

    // ---- final l reduction (once, 16-lane row groups)
#pragma unroll
    for (int msk = 1; msk <= 8; msk <<= 1)
#pragma unroll
        for (int r = 0; r < 4; ++r) {
            rsA[r] += __shfl_xor(rsA[r], msk);
            rsB[r] += __shfl_xor(rsB[r], msk);
        }

    // ---- epilogue
    size_t obase = ((size_t)z * NH_ + h) * S_ * HD_;
#pragma unroll
    for (int r = 0; r < 4; ++r) {
        int qa = qbase + quad * 4 + r;
        if (qa < S_) {
            float inv = 1.f / rsA[r];
            float* dst = out + obase + (size_t)qa * HD_ + lq;
            dst[0]  = oA[0][r] * inv;
            dst[16] = oA[1][r] * inv;
            dst[32] = oA[2][r] * inv;
            dst[48] = oA[3][r] * inv;
        }
        int qb = qbase + 16 + quad * 4 + r;
        if (qb < S_) {
            float inv = 1.f / rsB[r];
            float* dst = out + obase + (size_t)qb * HD_ + lq;
            dst[0]  = oB[0][r] * inv;
            dst[16] = oB[1][r] * inv;
            dst[32] = oB[2][r] * inv;
            dst[48] = oB[3][r] * inv;
        }
    }
}

// ---------------------------------------------------------------------------
extern "C" void kernel_launch(void* const* d_in, const int* in_sizes, int n_in,
                              void* d_out, int out_size, void* d_ws, size_t ws_size,
                              hipStream_t stream) {
    (void)in_sizes; (void)n_in; (void)out_size; (void)ws_size;
    const float* x1    = (const float*)d_in[0];
    const float* x2    = (const float*)d_in[3];
    const float* dw    = (const float*)d_in[6];
    const float* gamma = (const float*)d_in[7];
    const float* beta  = (const float*)d_in[8];
    const float* pw    = (const float*)d_in[9];
    const float* pwb   = (const float*)d_in[10];
    const float* lin   = (const float*)d_in[11];
    float* out = (float*)d_out;

    char* ws = (char*)d_ws;
    // ws layout (bytes):
    // y    bf16 [9][16][784][384]  @ 28901376   size 86,704,128
    // qkv  bf16 [9][16][784][384]  @ 115605504  size 86,704,128
    // Wcb  bf16 [9][384][384]      @ 202309632  size 2,654,208
    // Bc   f32  [9][384]           @ 204963840  size 13,824
    // part f32  [9][384][2]        @ 205005312  size 27,648 (memset to 0)
    u16*  y   = (u16*)(ws + 28901376);
    u16*  qkv = (u16*)(ws + 115605504);
    u16*  Wcb = (u16*)(ws + 202309632);
    float* Bc = (float*)(ws + 204963840);
    float* part = (float*)(ws + 205005312);

    hipMemsetAsync(part, 0, 9 * C_ * 2 * sizeof(float), stream);
    k_conv  <<<dim3(4032), 128, 0, stream>>>(x1, x2, dw, y, part);
    k_wcomb <<<dim3(864), 384, 0, stream>>>(pw, pwb, lin, part, gamma, beta, Wcb, Bc);
    k_gemm  <<<dim3(3024), 256, 0, stream>>>(y, Wcb, Bc, qkv);
    k_attn  <<<dim3(2016), 256, 0, stream>>>(qkv, out);
}

// Round 10
// 412.030 us; speedup vs baseline: 1.1060x; 1.0302x over previous
//
#include <hip/hip_runtime.h>

typedef unsigned short u16;
typedef unsigned int u32;
typedef unsigned long long u64;

#define B_   16
#define C_   384
#define H_   28
#define W_   28
#define S_   784
#define NH_  6
#define HD_  64
#define BS_  (B_ * S_)            // 12544
#define SCALE_ 0.05103103630798288f  // 384^-0.5
#define LSC_   0.07362225484151387f  // SCALE_ * log2(e): exp(s*SCALE) = 2^(s*LSC)
#define EPS_ 1e-5f

typedef __attribute__((ext_vector_type(8))) short bf16x8;
typedef __attribute__((ext_vector_type(4))) float f32x4;
typedef __attribute__((ext_vector_type(2))) float f32x2;

__device__ __forceinline__ float bf2f(u16 u) {
    return __uint_as_float(((u32)u) << 16);
}
__device__ __forceinline__ u16 f2bf(float f) {
    u32 x = __float_as_uint(f);
    u32 r = (x + 0x7fffu + ((x >> 16) & 1u)) >> 16;   // RNE
    return (u16)r;
}

// async global->LDS 16B per lane; dest = wave-uniform base + lane*16 (HW rule)
__device__ __forceinline__ void gld16(const u16* g, u16* l) {
    __builtin_amdgcn_global_load_lds(
        (__attribute__((address_space(1))) void*)g,
        (__attribute__((address_space(3))) void*)l, 16, 0, 0);
}

__device__ __forceinline__ float exp2_fast(float x) {
    float r;
    asm("v_exp_f32 %0, %1" : "=v"(r) : "v"(x));
    return r;
}

// ---------------------------------------------------------------------------
// Kernel 2 (fused, 3-in-1 by input group): depthwise 3x3 conv.
// R10: (a) 2 CHANNELS PER THREAD -- float2 loads (8B/lane), packed-u32 bf16
// stores (4B/lane). Conv was pure scalar-4B/2B traffic: 168 load + 84 store
// insts/thread (Guideline-13 violation); this halves memory instruction
// count and waitcnt serialization for the same bytes. Per-channel FP
// sequence unchanged. (b) PER-XCD ATOMIC SLABS part[xcd][idx][c][2]: the
// flat part[] had 448 sharers/address spread across all 8 XCDs -> every
// atomicAdd was a cross-XCD RMW at the coherence point (~500cy, HBM
// write-through). Same atomic count, now 56 same-XCD sharers, no line
// bouncing. k_wcomb prologue sums the 8 slabs.
// Branch-free blend + loads-first + XCD/halo swizzle kept from R9.
// ---------------------------------------------------------------------------
__launch_bounds__(192)
__global__ void k_conv(const float* __restrict__ x1, const float* __restrict__ x2,
                       const float* __restrict__ dw, u16* __restrict__ y,
                       float* __restrict__ part) {
    int id = blockIdx.x;            // 0..1343
    int xcd = id & 7;
    int j = id >> 3;                // 0..167
    int p = xcd + 8 * (j / 28);     // 0..47
    int h = j % 28;                 // 0..27
    int g = p / 16;                 // input group (wave-uniform)
    int b = p % 16;
    int tid = threadIdx.x;          // 0..191
    int c0 = tid * 2;               // channel pair c0, c0+1

    const f32x2* pa = (const f32x2*)x1 + (size_t)b * S_ * 192 + tid;
    const f32x2* pb = (const f32x2*)x2 + (size_t)b * S_ * 192 + tid;
    float s0 = (g == 1) ? 0.f : 1.f;    // x1 blend weight
    float s1 = (g == 0) ? 0.f : 1.f;    // x2 blend weight

    f32x2 wt[3][9];
#pragma unroll
    for (int i = 0; i < 3; ++i)
#pragma unroll
        for (int t = 0; t < 9; ++t) {
            wt[i][t][0] = dw[((3 * g + i) * C_ + c0) * 9 + t];
            wt[i][t][1] = dw[((3 * g + i) * C_ + c0 + 1) * 9 + t];
        }

    // per-row 0/1 masks + clamped row offsets (f32x2 units)
    float rm[3];
    int ro[3];
#pragma unroll
    for (int dh = 0; dh < 3; ++dh) {
        int hh = h + dh - 1;
        rm[dh] = (hh >= 0 && hh < H_) ? 1.f : 0.f;
        int hc = hh < 0 ? 0 : (hh > H_ - 1 ? H_ - 1 : hh);
        ro[dh] = hc * W_ * 192;
    }

    // sliding window: a[dh][0..2] = cols w-1, w, w+1 (blended, masked)
    f32x2 a[3][3];
#pragma unroll
    for (int dh = 0; dh < 3; ++dh) {
        f32x2 v1 = pa[ro[dh]],       w1 = pb[ro[dh]];
        f32x2 v2 = pa[ro[dh] + 192], w2 = pb[ro[dh] + 192];
        a[dh][0] = (f32x2){0.f, 0.f};
        a[dh][1] = (v1 * s0 + w1 * s1) * rm[dh];
        a[dh][2] = (v2 * s0 + w2 * s1) * rm[dh];
    }

    u32* du[3];
#pragma unroll
    for (int i = 0; i < 3; ++i)
        du[i] = (u32*)(y + ((size_t)((3 * g + i) * B_ + b) * S_ + h * W_) * C_ + c0);

    f32x2 sum[3], sq[3];
#pragma unroll
    for (int i = 0; i < 3; ++i) { sum[i] = (f32x2){0.f, 0.f}; sq[i] = sum[i]; }

#pragma unroll 4
    for (int w = 0; w < W_; ++w) {
        // ---- next column: 6x 8B loads in one burst (branch-free)
        int wn = w + 2;
        float wm = (wn < W_) ? 1.f : 0.f;
        int wc = (wn < W_) ? wn : (W_ - 1);
        f32x2 la0 = pa[ro[0] + wc * 192], lb0 = pb[ro[0] + wc * 192];
        f32x2 la1 = pa[ro[1] + wc * 192], lb1 = pb[ro[1] + wc * 192];
        f32x2 la2 = pa[ro[2] + wc * 192], lb2 = pb[ro[2] + wc * 192];
        f32x2 nx0 = (la0 * s0 + lb0 * s1) * (rm[0] * wm);
        f32x2 nx1 = (la1 * s0 + lb1 * s1) * (rm[1] * wm);
        f32x2 nx2 = (la2 * s0 + lb2 * s1) * (rm[2] * wm);

        // ---- compute + packed stores
#pragma unroll
        for (int i = 0; i < 3; ++i) {
            f32x2 acc = a[0][0]*wt[i][0] + a[0][1]*wt[i][1] + a[0][2]*wt[i][2]
                      + a[1][0]*wt[i][3] + a[1][1]*wt[i][4] + a[1][2]*wt[i][5]
                      + a[2][0]*wt[i][6] + a[2][1]*wt[i][7] + a[2][2]*wt[i][8];
            sum[i] += acc;
            sq[i] += acc * acc;
            u32 pk = (u32)f2bf(acc[0]) | ((u32)f2bf(acc[1]) << 16);
            du[i][w * 192] = pk;
        }
        // ---- slide (renamed away by unroll)
        a[0][0] = a[0][1]; a[0][1] = a[0][2]; a[0][2] = nx0;
        a[1][0] = a[1][1]; a[1][1] = a[1][2]; a[1][2] = nx1;
        a[2][0] = a[2][1]; a[2][1] = a[2][2]; a[2][2] = nx2;
    }
    float* ps = part + xcd * (9 * C_ * 2);   // per-XCD slab
#pragma unroll
    for (int i = 0; i < 3; ++i) {
        atomicAdd(&ps[((3 * g + i) * C_ + c0) * 2],         sum[i][0]);
        atomicAdd(&ps[((3 * g + i) * C_ + c0) * 2 + 1],     sq[i][0]);
        atomicAdd(&ps[((3 * g + i) * C_ + c0 + 1) * 2],     sum[i][1]);
        atomicAdd(&ps[((3 * g + i) * C_ + c0 + 1) * 2 + 1], sq[i][1]);
    }
}

// ---------------------------------------------------------------------------
// Kernel 4: combined weights. Wcb (bf16) [idx][o][c] = lin@pw * aScale[c];
// Bc[idx][o] = (lin@pw)@bShift + lin@pwb.
// R10: prologue sums the 8 per-XCD part slabs (16 loads), then BN finalize.
// R8 structure otherwise: grid 864, XCD-aware idx mapping, 8x m-unroll.
// ---------------------------------------------------------------------------
__global__ void k_wcomb(const float* __restrict__ pw, const float* __restrict__ pwb,
                        const float* __restrict__ lin,
                        const float* __restrict__ part,
                        const float* __restrict__ gamma, const float* __restrict__ beta,
                        u16* __restrict__ Wcb, float* __restrict__ Bc) {
    __shared__ float red[8];
    int id = blockIdx.x;            // 0..863
    int xcd = id & 7;
    int k2 = id >> 3;               // 0..107
    int idx, og;
    if (k2 < 96) { idx = xcd; og = k2; }
    else         { idx = 8;   og = xcd * 12 + (k2 - 96); }
    int c = threadIdx.x;            // 0..383
    int wave = c >> 6, lane = c & 63;
    int li = (idx < 3) ? idx : 3 + (idx % 3);   // replicate branch-2 lin reuse bug

    // sum per-XCD slabs, then inline BN finalize (same downstream op order)
    float s_ = 0.f, q_ = 0.f;
#pragma unroll
    for (int x = 0; x < 8; ++x) {
        s_ += part[x * (9 * C_ * 2) + (idx * C_ + c) * 2];
        q_ += part[x * (9 * C_ * 2) + (idx * C_ + c) * 2 + 1];
    }
    float mean = s_ / (float)BS_;
    float var  = q_ / (float)BS_ - mean * mean;
    float aS = gamma[idx * C_ + c] * rsqrtf(var + EPS_);
    float bS = beta[idx * C_ + c] - mean * aS;

    float acc[4];
#pragma unroll
    for (int k = 0; k < 4; ++k) acc[k] = 0.f;
    const float* pwm = pw + (idx * C_) * C_ + c;
    const float* lb  = lin + ((li * C_) + og * 4) * C_;

    float pvv[8];
#pragma unroll
    for (int u = 0; u < 8; ++u) pvv[u] = pwm[u * C_];
    for (int m0 = 0; m0 < C_; m0 += 8) {
        float pvn[8];
        if (m0 + 8 < C_) {
#pragma unroll
            for (int u = 0; u < 8; ++u) pvn[u] = pwm[(m0 + 8 + u) * C_];
        } else {
#pragma unroll
            for (int u = 0; u < 8; ++u) pvn[u] = 0.f;
        }
#pragma unroll
        for (int u = 0; u < 8; ++u) {
            float pv = pvv[u];
#pragma unroll
            for (int k = 0; k < 4; ++k)
                acc[k] += lb[k * C_ + (m0 + u)] * pv;
        }
#pragma unroll
        for (int u = 0; u < 8; ++u) pvv[u] = pvn[u];
    }

    float pwbc = pwb[idx * C_ + c];
    for (int k = 0; k < 4; ++k) {
        int o = og * 4 + k;
        Wcb[(idx * C_ + o) * C_ + c] = f2bf(acc[k] * aS);
        float v = acc[k] * bS + lin[(li * C_ + o) * C_ + c] * pwbc;
#pragma unroll
        for (int msk = 1; msk < 64; msk <<= 1) v += __shfl_xor(v, msk);
        if (lane == 0) red[wave] = v;
        __syncthreads();
        if (c == 0)
            Bc[idx * C_ + o] = red[0] + red[1] + red[2] + red[3] + red[4] + red[5];
        __syncthreads();
    }
}

// ---------------------------------------------------------------------------
// Kernel 5: MFMA GEMM, m97 structure: 128x128 tile, BK=32, double-buffered
// LDS staged via global_load_lds(16B), 1 barrier per K-step.
// ---------------------------------------------------------------------------
__launch_bounds__(256)
__global__ void k_gemm(const u16* __restrict__ y, const u16* __restrict__ Wcb,
                       const float* __restrict__ Bc, u16* __restrict__ qkv) {
    __shared__ __align__(16) u16 ldsA[2][4096];   // [stage][128 rows][4 chunks*8]
    __shared__ __align__(16) u16 ldsB[2][4096];

    int id = blockIdx.x;            // 0..3023
    int xcd = id & 7;
    int kb = id >> 3;               // 0..377
    int zz = kb / 21;               // 0..17
    int t  = kb % 21;
    int z  = zz * 8 + xcd;          // 0..143
    int by = t / 7, bx = t % 7;
    int idx = z >> 4, b = z & 15;

    int tid = threadIdx.x;
    int wave = tid >> 6;
    int lane = tid & 63;
    int lq = lane & 15;
    int quad = lane >> 4;
    int o_base = by * 128 + (wave & 1) * 64;          // for bias/epilogue
    int s_base_w = bx * 128 + (wave >> 1) * 64;       // for epilogue

    const u16* ybase = y + (size_t)(idx * B_ + b) * S_ * C_;
    const u16* wbase = Wcb + (size_t)idx * C_ * C_;

    // staging geometry: element e = i*256+tid covers 16B; row r=e>>2, chunk q=e&3
    int r0 = tid >> 2;              // issue-0 row (0..63); issue-1 adds 64
    int qs = (tid & 3) ^ ((r0 ^ (r0 >> 2)) & 3);   // swizzle invariant under +64
    int srA0 = bx * 128 + r0;       if (srA0 > S_ - 1) srA0 = S_ - 1;
    int srA1 = bx * 128 + r0 + 64;  if (srA1 > S_ - 1) srA1 = S_ - 1;
    const u16* gA0 = ybase + (size_t)srA0 * C_ + qs * 8;
    const u16* gA1 = ybase + (size_t)srA1 * C_ + qs * 8;
    const u16* gB0 = wbase + (size_t)(by * 128 + r0) * C_ + qs * 8;
    const u16* gB1 = wbase + (size_t)(by * 128 + r0 + 64) * C_ + qs * 8;
    int lo0 = wave * 512;           // u16 idx: wave base, issue 0
    int lo1 = 2048 + wave * 512;    // issue 1

#define STAGE(stg, kk) do {                          \
        gld16(gA0 + (kk) * 32, &ldsA[stg][lo0]);     \
        gld16(gA1 + (kk) * 32, &ldsA[stg][lo1]);     \
        gld16(gB0 + (kk) * 32, &ldsB[stg][lo0]);     \
        gld16(gB1 + (kk) * 32, &ldsB[stg][lo1]);     \
    } while (0)

    f32x4 acc[4][4];
#pragma unroll
    for (int i = 0; i < 4; ++i)
#pragma unroll
        for (int j2 = 0; j2 < 4; ++j2) acc[i][j2] = (f32x4){0.f,0.f,0.f,0.f};

    STAGE(0, 0);
    __syncthreads();

    int qoff = (quad ^ ((lq ^ (lq >> 2)) & 3)) * 8;   // read-side swizzle
    bf16x8 af[4], bw[4];
#pragma unroll
    for (int ks = 0; ks < 12; ++ks) {
        int cur = ks & 1;
        if (ks < 11) STAGE(cur ^ 1, ks + 1);          // async into other buffer
#pragma unroll
        for (int mt = 0; mt < 4; ++mt) {
            int sl = (wave >> 1) * 64 + mt * 16 + lq;
            __builtin_memcpy(&af[mt], &ldsA[cur][sl * 32 + qoff], 16);
        }
#pragma unroll
        for (int nt = 0; nt < 4; ++nt) {
            int ol = (wave & 1) * 64 + nt * 16 + lq;
            __builtin_memcpy(&bw[nt], &ldsB[cur][ol * 32 + qoff], 16);
        }
#pragma unroll
        for (int mt = 0; mt < 4; ++mt)
#pragma unroll
            for (int nt = 0; nt < 4; ++nt)
                acc[mt][nt] = __builtin_amdgcn_mfma_f32_16x16x32_bf16(
                    af[mt], bw[nt], acc[mt][nt], 0, 0, 0);
        __syncthreads();    // drains this step's stage (vmcnt) + frees cur buf
    }
#undef STAGE

    float bias[4];
#pragma unroll
    for (int nt = 0; nt < 4; ++nt) bias[nt] = Bc[idx * C_ + o_base + nt * 16 + lq];
    u16* obase = qkv + ((size_t)(idx * B_ + b) * S_) * C_;
#pragma unroll
    for (int mt = 0; mt < 4; ++mt) {
#pragma unroll
        for (int r = 0; r < 4; ++r) {
            int s = s_base_w + mt * 16 + quad * 4 + r;
            if (s >= S_) continue;
            u16* row = obase + (size_t)s * C_ + o_base + lq;
#pragma unroll
            for (int nt = 0; nt < 4; ++nt)
                row[nt * 16] = f2bf(acc[mt][nt][r] + bias[nt]);
        }
    }
}

// ---------------------------------------------------------------------------
// Kernel 6: MFMA flash attention, M=32/wave, no-max softmax, T=64 chunks.
// R5 structure (packed P, swizzled V b128 reads, exp2, tail split),
// __launch_bounds__(256,4). Unchanged.
// ---------------------------------------------------------------------------
__launch_bounds__(256, 4)
__global__ void k_attn(const u16* __restrict__ qkv, float* __restrict__ out) {
    __shared__ __align__(16) u16 sm[12544];   // V 8192 B @0; P 4*4224 B @8192

    int id = blockIdx.x;
    int g8 = id & 7;
    int rest = id >> 3;             // 0..251
    int qtile = rest % 7;           // 0..6
    int zh = (rest / 7) * 8 + g8;   // 0..287
    int z = zh / 6, h = zh % 6;     // z: br*16+b
    int br = z >> 4;
    int tid = threadIdx.x;
    int wave = tid >> 6;
    int lane = tid & 63;
    int lq = lane & 15;
    int quad = lane >> 4;

    int idxq = 3 * br;
    const u16* qp = qkv + (size_t)((idxq * B_ + (z & 15)) * S_) * C_ + h * HD_;
    const u16* kp = qkv + (size_t)(((idxq + 1) * B_ + (z & 15)) * S_) * C_ + h * HD_;
    const u16* vp = qkv + (size_t)(((idxq + 2) * B_ + (z & 15)) * S_) * C_ + h * HD_;

    int qbase = qtile * 128 + wave * 32;
    int qrA = qbase + lq;      if (qrA > S_ - 1) qrA = S_ - 1;
    int qrB = qbase + 16 + lq; if (qrB > S_ - 1) qrB = S_ - 1;
    const u16* qpa = qp + (size_t)qrA * C_ + quad * 8;
    const u16* qpb = qp + (size_t)qrB * C_ + quad * 8;
    bf16x8 aqA0 = *(const bf16x8*)qpa;
    bf16x8 aqA1 = *(const bf16x8*)(qpa + 32);
    bf16x8 aqB0 = *(const bf16x8*)qpb;
    bf16x8 aqB1 = *(const bf16x8*)(qpb + 32);

    f32x4 oA[4], oB[4];
#pragma unroll
    for (int i = 0; i < 4; ++i) { oA[i] = (f32x4){0.f,0.f,0.f,0.f}; oB[i] = oA[i]; }
    float rsA[4] = {0.f,0.f,0.f,0.f}, rsB[4] = {0.f,0.f,0.f,0.f};

    // V staging: 2 consecutive t, 8 d per thread (256 thr cover 64t x 64d)
    int t2 = (tid & 31) * 2;        // 0..62
    int dg = (tid >> 5) * 8;        // 0..56
    char* smb = (char*)sm;
    // V write addresses: byte = d*128 + ((t2/8 ^ (d&7))<<4) + (t2&7)*2, d=dg+e
    // P buffer (u32 view): per-wave base, rows=q (0..15), stride 66 u32
    u32* pb0 = (u32*)sm + 2048 + wave * 1056;
    u32* pwr = pb0 + (quad * 4) * 66 + lq;       // store base: + r*66 + tt*16
    const u32* prd = pb0 + lq * 66 + quad * 8;   // read base: + n*32 + j
    int sw = lq & 7;                              // V read swizzle key
    int vrb0 = lq * 128 + ((quad ^ sw) << 4);          // kh=0 V-frag byte base
    int vrb1 = lq * 128 + (((4 + quad) ^ sw) << 4);    // kh=1

#define VSTAGE(TG0, TG1) do {                                              \
        bf16x8 v0 = *(const bf16x8*)(vp + (size_t)(TG0) * C_ + dg);        \
        bf16x8 v1 = *(const bf16x8*)(vp + (size_t)(TG1) * C_ + dg);        \
        __syncthreads();                                                   \
        _Pragma("unroll")                                                  \
        for (int e = 0; e < 8; ++e) {                                      \
            u32 pk = (u32)(u16)v0[e] | ((u32)(u16)v1[e] << 16);            \
            *(u32*)(smb + (dg + e) * 128 + ((((t2 >> 3) ^ e)) << 4)        \
                    + ((t2 & 7) << 1)) = pk;                               \
        }                                                                  \
        __syncthreads();                                                   \
    } while (0)

    for (int ch = 0; ch < 12; ++ch) {
        int tc = ch * 64;
        VSTAGE(tc + t2, tc + t2 + 1);

        // ---- QK^T + exp + packed P-store, per 16-t tile (all t live)
#pragma unroll
        for (int tt = 0; tt < 4; ++tt) {
            const u16* kptr = kp + (size_t)(tc + tt * 16 + lq) * C_ + quad * 8;
            bf16x8 bk0 = *(const bf16x8*)kptr;
            bf16x8 bk1 = *(const bf16x8*)(kptr + 32);
            f32x4 sA = {0.f,0.f,0.f,0.f}, sB = sA;
            sA = __builtin_amdgcn_mfma_f32_16x16x32_bf16(aqA0, bk0, sA, 0, 0, 0);
            sA = __builtin_amdgcn_mfma_f32_16x16x32_bf16(aqA1, bk1, sA, 0, 0, 0);
            sB = __builtin_amdgcn_mfma_f32_16x16x32_bf16(aqB0, bk0, sB, 0, 0, 0);
            sB = __builtin_amdgcn_mfma_f32_16x16x32_bf16(aqB1, bk1, sB, 0, 0, 0);
#pragma unroll
            for (int r = 0; r < 4; ++r) {
                float ea = exp2_fast(sA[r] * LSC_);
                float eb = exp2_fast(sB[r] * LSC_);
                u32 ua = __float_as_uint(ea) & 0xFFFF0000u;   // trunc bf16
                u32 ub = __float_as_uint(eb) & 0xFFFF0000u;
                rsA[r] += __uint_as_float(ua);    // consistent w/ numerator
                rsB[r] += __uint_as_float(ub);
                // pk = {eb.hi16, ea.hi16}
                pwr[r * 66 + tt * 16] = __builtin_amdgcn_perm(
                    __float_as_uint(eb), __float_as_uint(ea), 0x07060302u);
            }
        }

        // ---- P A-frags (shared reads, perm unpack; memcpy orders vs stores)
        bf16x8 apA[2], apB[2];
#pragma unroll
        for (int n = 0; n < 2; ++n) {
            u32 uu[8];
            __builtin_memcpy(uu, prd + n * 32, 32);
            union { u32 w[4]; bf16x8 v; } ca, cb;
#pragma unroll
            for (int jj = 0; jj < 4; ++jj) {
                ca.w[jj] = __builtin_amdgcn_perm(uu[2*jj+1], uu[2*jj], 0x05040100u);
                cb.w[jj] = __builtin_amdgcn_perm(uu[2*jj+1], uu[2*jj], 0x07060302u);
            }
            apA[n] = ca.v; apB[n] = cb.v;
        }

        // ---- PV: swizzled aligned b128 V-frags, shared by both rowsets
#pragma unroll
        for (int dt = 0; dt < 4; ++dt) {
            bf16x8 bv0, bv1;
            __builtin_memcpy(&bv0, smb + dt * 2048 + vrb0, 16);
            __builtin_memcpy(&bv1, smb + dt * 2048 + vrb1, 16);
            oA[dt] = __builtin_amdgcn_mfma_f32_16x16x32_bf16(apA[0], bv0, oA[dt], 0, 0, 0);
            oB[dt] = __builtin_amdgcn_mfma_f32_16x16x32_bf16(apB[0], bv0, oB[dt], 0, 0, 0);
            oA[dt] = __builtin_amdgcn_mfma_f32_16x16x32_bf16(apA[1], bv1, oA[dt], 0, 0, 0);
            oB[dt] = __builtin_amdgcn_mfma_f32_16x16x32_bf16(apB[1], bv1, oB[dt], 0, 0, 0);
        }
    }

    // ---- tail chunk: t 768..783 live (16 of 64)
    {
        int tc = 768;
        int tg0 = tc + t2;     if (tg0 > S_ - 1) tg0 = S_ - 1;
        int tg1 = tc + t2 + 1; if (tg1 > S_ - 1) tg1 = S_ - 1;
        VSTAGE(tg0, tg1);

        const u16* kptr = kp + (size_t)(tc + lq) * C_ + quad * 8;
        bf16x8 bk0 = *(const bf16x8*)kptr;
        bf16x8 bk1 = *(const bf16x8*)(kptr + 32);
        f32x4 sA = {0.f,0.f,0.f,0.f}, sB = sA;
        sA = __builtin_amdgcn_mfma_f32_16x16x32_bf16(aqA0, bk0, sA, 0, 0, 0);
        sA = __builtin_amdgcn_mfma_f32_16x16x32_bf16(aqA1, bk1, sA, 0, 0, 0);
        sB = __builtin_amdgcn_mfma_f32_16x16x32_bf16(aqB0, bk0, sB, 0, 0, 0);
        sB = __builtin_amdgcn_mfma_f32_16x16x32_bf16(aqB1, bk1, sB, 0, 0, 0);
#pragma unroll
        for (int r = 0; r < 4; ++r) {
            float ea = exp2_fast(sA[r] * LSC_);
            float eb = exp2_fast(sB[r] * LSC_);
            u32 ua = __float_as_uint(ea) & 0xFFFF0000u;
            u32 ub = __float_as_uint(eb) & 0xFFFF0000u;
            rsA[r] += __uint_as_float(ua);
            rsB[r] += __uint_as_float(ub);
            pwr[r * 66]      = __builtin_amdgcn_perm(
                __float_as_uint(eb), __float_as_uint(ea), 0x07060302u);
            pwr[r * 66 + 16] = 0;               // zero t 16..31 (dead)
        }

        bf16x8 apA0, apB0;
        {
            u32 uu[8];
            __builtin_memcpy(uu, prd, 32);
            union { u32 w[4]; bf16x8 v; } ca, cb;
#pragma unroll
            for (int jj = 0; jj < 4; ++jj) {
                ca.w[jj] = __builtin_amdgcn_perm(uu[2*jj+1], uu[2*jj], 0x05040100u);
                cb.w[jj] = __builtin_amdgcn_perm(uu[2*jj+1], uu[2*jj], 0x07060302u);
            }
            apA0 = ca.v; apB0 = cb.v;
        }
#pragma unroll
        for (int dt = 0; dt < 4; ++dt) {
            bf16x8 bv0;
            __builtin_memcpy(&bv0, smb + dt * 2048 + vrb0, 16);
            oA[dt] = __builtin_amdgcn_mfma_f32_16x16x32_bf16(apA0, bv0, oA[dt], 0, 0, 0);
            oB[dt] = __builtin_amdgcn_mfma_f32_16x16x32_bf16(apB0, bv0, oB[dt], 0, 0, 0);
        }
    }
#undef VSTAGE

    // ---- final l reduction (once, 16-lane row groups)
#pragma unroll
    for (int msk = 1; msk <= 8; msk <<= 1)
#pragma unroll
        for (int r = 0; r < 4; ++r) {
            rsA[r] += __shfl_xor(rsA[r], msk);
            rsB[r] += __shfl_xor(rsB[r], msk);
        }

    // ---- epilogue
    size_t obase = ((size_t)z * NH_ + h) * S_ * HD_;
#pragma unroll
    for (int r = 0; r < 4; ++r) {
        int qa = qbase + quad * 4 + r;
        if (qa < S_) {
            float inv = 1.f / rsA[r];
            float* dst = out + obase + (size_t)qa * HD_ + lq;
            dst[0]  = oA[0][r] * inv;
            dst[16] = oA[1][r] * inv;
            dst[32] = oA[2][r] * inv;
            dst[48] = oA[3][r] * inv;
        }
        int qb = qbase + 16 + quad * 4 + r;
        if (qb < S_) {
            float inv = 1.f / rsB[r];
            float* dst = out + obase + (size_t)qb * HD_ + lq;
            dst[0]  = oB[0][r] * inv;
            dst[16] = oB[1][r] * inv;
            dst[32] = oB[2][r] * inv;
            dst[48] = oB[3][r] * inv;
        }
    }
}

// ---------------------------------------------------------------------------
extern "C" void kernel_launch(void* const* d_in, const int* in_sizes, int n_in,
                              void* d_out, int out_size, void* d_ws, size_t ws_size,
                              hipStream_t stream) {
    (void)in_sizes; (void)n_in; (void)out_size; (void)ws_size;
    const float* x1    = (const float*)d_in[0];
    const float* x2    = (const float*)d_in[3];
    const float* dw    = (const float*)d_in[6];
    const float* gamma = (const float*)d_in[7];
    const float* beta  = (const float*)d_in[8];
    const float* pw    = (const float*)d_in[9];
    const float* pwb   = (const float*)d_in[10];
    const float* lin   = (const float*)d_in[11];
    float* out = (float*)d_out;

    char* ws = (char*)d_ws;
    // ws layout (bytes):
    // part f32  [8][9][384][2]     @ 0          size 221,184 (memset to 0)
    // y    bf16 [9][16][784][384]  @ 28901376   size 86,704,128
    // qkv  bf16 [9][16][784][384]  @ 115605504  size 86,704,128
    // Wcb  bf16 [9][384][384]      @ 202309632  size 2,654,208
    // Bc   f32  [9][384]           @ 204963840  size 13,824
    float* part = (float*)(ws + 0);
    u16*  y   = (u16*)(ws + 28901376);
    u16*  qkv = (u16*)(ws + 115605504);
    u16*  Wcb = (u16*)(ws + 202309632);
    float* Bc = (float*)(ws + 204963840);

    hipMemsetAsync(part, 0, 8 * 9 * C_ * 2 * sizeof(float), stream);
    k_conv  <<<dim3(1344), 192, 0, stream>>>(x1, x2, dw, y, part);
    k_wcomb <<<dim3(864), 384, 0, stream>>>(pw, pwb, lin, part, gamma, beta, Wcb, Bc);
    k_gemm  <<<dim3(3024), 256, 0, stream>>>(y, Wcb, Bc, qkv);
    k_attn  <<<dim3(2016), 256, 0, stream>>>(qkv, out);
}